// Round 2
// baseline (359.473 us; speedup 1.0000x reference)
//
#include <hip/hip_runtime.h>
#include <math.h>

#define D_MODEL 1024
#define N_HEADS 16
#define DKH     64
#define BATCH   2
#define SEQ     2048

typedef unsigned short u16;
typedef __attribute__((ext_vector_type(8))) short short8;
typedef __attribute__((ext_vector_type(4))) float f32x4;

__device__ __forceinline__ u16 f2bf(float f) {
    unsigned u = __float_as_uint(f);
    u += 0x7fffu + ((u >> 16) & 1u);
    return (u16)(u >> 16);
}

// C = X @ W^T + bias.  X:(M,K) fp32 row-major, W:(N,K) fp32 row-major.
// MODE 0: dst = fp32 (M,N) row-major, value = (acc+bias)*scale
// MODE 1: dst = bf16 scattered to (B, H, S, dk):  m=b*SEQ+s, n=h*64+d
// MODE 2: dst = bf16 scattered to (B, H, dk, S) [transposed for PV B-fragments]
template<int MODE>
__global__ __launch_bounds__(256)
void gemm_bias_kernel(const float* __restrict__ X, const float* __restrict__ W,
                      const float* __restrict__ bias, float scale,
                      void* __restrict__ dst, int M, int N, int K)
{
    __shared__ __align__(16) u16 As[64][40];   // 64 rows x 32 cols, +8 pad (80B stride)
    __shared__ __align__(16) u16 Bs[64][40];

    const int tid  = threadIdx.x;
    const int lane = tid & 63;
    const int wid  = tid >> 6;          // 4 waves: 2x2 over the 64x64 tile
    const int wm   = wid >> 1, wn = wid & 1;
    const int lr   = lane & 15, lg = lane >> 4;
    const int mb   = blockIdx.x * 64, nb = blockIdx.y * 64;

    const int srow = tid >> 2;          // staging: 0..63
    const int scol = (tid & 3) << 3;    // 0,8,16,24

    f32x4 acc00 = {0.f,0.f,0.f,0.f};
    f32x4 acc01 = acc00, acc10 = acc00, acc11 = acc00;

    const float* xrow = X + (size_t)(mb + srow) * K + scol;
    const float* wrow = W + (size_t)(nb + srow) * K + scol;

    for (int kt = 0; kt < K; kt += 32) {
        __syncthreads();
        float4 x0 = *(const float4*)(xrow + kt);
        float4 x1 = *(const float4*)(xrow + kt + 4);
        short8 av;
        av[0]=(short)f2bf(x0.x); av[1]=(short)f2bf(x0.y); av[2]=(short)f2bf(x0.z); av[3]=(short)f2bf(x0.w);
        av[4]=(short)f2bf(x1.x); av[5]=(short)f2bf(x1.y); av[6]=(short)f2bf(x1.z); av[7]=(short)f2bf(x1.w);
        *(short8*)&As[srow][scol] = av;
        float4 w0 = *(const float4*)(wrow + kt);
        float4 w1 = *(const float4*)(wrow + kt + 4);
        short8 bvv;
        bvv[0]=(short)f2bf(w0.x); bvv[1]=(short)f2bf(w0.y); bvv[2]=(short)f2bf(w0.z); bvv[3]=(short)f2bf(w0.w);
        bvv[4]=(short)f2bf(w1.x); bvv[5]=(short)f2bf(w1.y); bvv[6]=(short)f2bf(w1.z); bvv[7]=(short)f2bf(w1.w);
        *(short8*)&Bs[srow][scol] = bvv;
        __syncthreads();

        short8 a0 = *(short8*)&As[wm*32 +  0 + lr][lg*8];
        short8 a1 = *(short8*)&As[wm*32 + 16 + lr][lg*8];
        short8 b0 = *(short8*)&Bs[wn*32 +  0 + lr][lg*8];
        short8 b1 = *(short8*)&Bs[wn*32 + 16 + lr][lg*8];
        acc00 = __builtin_amdgcn_mfma_f32_16x16x32_bf16(a0, b0, acc00, 0, 0, 0);
        acc01 = __builtin_amdgcn_mfma_f32_16x16x32_bf16(a0, b1, acc01, 0, 0, 0);
        acc10 = __builtin_amdgcn_mfma_f32_16x16x32_bf16(a1, b0, acc10, 0, 0, 0);
        acc11 = __builtin_amdgcn_mfma_f32_16x16x32_bf16(a1, b1, acc11, 0, 0, 0);
    }

    // epilogue
    #pragma unroll
    for (int i = 0; i < 2; ++i) {
        #pragma unroll
        for (int j = 0; j < 2; ++j) {
            f32x4 a = (i==0) ? (j==0 ? acc00 : acc01) : (j==0 ? acc10 : acc11);
            const int mbase = mb + wm*32 + i*16 + lg*4;
            const int n     = nb + wn*32 + j*16 + lr;
            const float bn  = bias[n];
            #pragma unroll
            for (int r = 0; r < 4; ++r) {
                const int m = mbase + r;
                const float val = (a[r] + bn) * scale;
                if (MODE == 0) {
                    ((float*)dst)[(size_t)m * N + n] = val;
                } else if (MODE == 1) {
                    const int b = m >> 11, s = m & (SEQ - 1);
                    const int h = n >> 6,  d = n & 63;
                    ((u16*)dst)[(((size_t)(b*N_HEADS + h))*SEQ + s)*DKH + d] = f2bf(val);
                } else {
                    const int b = m >> 11, s = m & (SEQ - 1);
                    const int h = n >> 6,  d = n & 63;
                    ((u16*)dst)[(((size_t)(b*N_HEADS + h))*DKH + d)*SEQ + s] = f2bf(val);
                }
            }
        }
    }
}

// Flash attention, causal. Qh/Kh: (B*H, S, 64) bf16 (Q pre-scaled by 1/8).
// Vt: (B*H, 64, S) bf16 (transposed).  attn out: (B, S, D_MODEL) fp32.
__global__ __launch_bounds__(256)
void flash_attn_kernel(const u16* __restrict__ Qh, const u16* __restrict__ Kh,
                       const u16* __restrict__ Vt, float* __restrict__ attn)
{
    __shared__ __align__(16) u16 P[4][16][72];   // per-wave P tile (16 q x 64 kv, +8 pad)

    const int tid  = threadIdx.x;
    const int lane = tid & 63;
    const int wid  = tid >> 6;
    const int lr   = lane & 15, lg = lane >> 4;
    const int qt   = blockIdx.x;            // q tile of 64
    const int bh   = blockIdx.y;            // b*H + h
    const int qbw  = qt*64 + wid*16;        // wave's first q row
    const size_t base = (size_t)bh * SEQ * DKH;   // same size for (S,64) and (64,S)

    // Q fragments (16 rows x 64 d) held in registers
    short8 aq0 = *(const short8*)&Qh[base + (size_t)(qbw + lr)*DKH +  0 + lg*8];
    short8 aq1 = *(const short8*)&Qh[base + (size_t)(qbw + lr)*DKH + 32 + lg*8];

    f32x4 o[4];
    float m_run[4], l_run[4];
    #pragma unroll
    for (int r = 0; r < 4; ++r) { m_run[r] = -INFINITY; l_run[r] = 0.f; }
    #pragma unroll
    for (int db = 0; db < 4; ++db) { f32x4 z = {0.f,0.f,0.f,0.f}; o[db] = z; }

    const int nc = qt + 1;                  // kv tiles of 64 needed (causal)
    for (int c = 0; c < nc; ++c) {
        const int kvb = c * 64;

        // S = Q K^T  (16 q x 64 kv), four 16-col blocks
        f32x4 s[4];
        #pragma unroll
        for (int cb = 0; cb < 4; ++cb) {
            f32x4 z = {0.f,0.f,0.f,0.f};
            const u16* kp = &Kh[base + (size_t)(kvb + cb*16 + lr)*DKH + lg*8];
            short8 k0 = *(const short8*)(kp);
            short8 k1 = *(const short8*)(kp + 32);
            z = __builtin_amdgcn_mfma_f32_16x16x32_bf16(aq0, k0, z, 0, 0, 0);
            z = __builtin_amdgcn_mfma_f32_16x16x32_bf16(aq1, k1, z, 0, 0, 0);
            s[cb] = z;
        }

        // causal mask (only relevant for the trailing tile)
        if (kvb + 63 > qbw) {
            #pragma unroll
            for (int cb = 0; cb < 4; ++cb)
                #pragma unroll
                for (int r = 0; r < 4; ++r)
                    if (kvb + cb*16 + lr > qbw + lg*4 + r) s[cb][r] = -INFINITY;
        }

        // online softmax (row = lg*4+r spread across 16-lane group lr)
        float alpha[4];
        #pragma unroll
        for (int r = 0; r < 4; ++r) {
            float tm = fmaxf(fmaxf(s[0][r], s[1][r]), fmaxf(s[2][r], s[3][r]));
            #pragma unroll
            for (int off = 1; off < 16; off <<= 1) tm = fmaxf(tm, __shfl_xor(tm, off));
            const float mnew = fmaxf(m_run[r], tm);
            alpha[r] = __expf(m_run[r] - mnew);     // m_run=-inf -> 0
            float ts = 0.f;
            #pragma unroll
            for (int cb = 0; cb < 4; ++cb) {
                const float p = __expf(s[cb][r] - mnew);
                P[wid][lg*4 + r][cb*16 + lr] = f2bf(p);
                ts += p;
            }
            #pragma unroll
            for (int off = 1; off < 16; off <<= 1) ts += __shfl_xor(ts, off);
            l_run[r] = l_run[r]*alpha[r] + ts;
            m_run[r] = mnew;
        }
        #pragma unroll
        for (int db = 0; db < 4; ++db)
            #pragma unroll
            for (int r = 0; r < 4; ++r) o[db][r] *= alpha[r];

        // O += P @ V   (two k-slices of 32, V fragments contiguous from Vt)
        #pragma unroll
        for (int ks = 0; ks < 2; ++ks) {
            short8 ap = *(short8*)&P[wid][lr][ks*32 + lg*8];
            #pragma unroll
            for (int db = 0; db < 4; ++db) {
                short8 bv = *(const short8*)&Vt[base + (size_t)(db*16 + lr)*SEQ
                                                + kvb + ks*32 + lg*8];
                o[db] = __builtin_amdgcn_mfma_f32_16x16x32_bf16(ap, bv, o[db], 0, 0, 0);
            }
        }
    }

    const int b = bh >> 4, h = bh & 15;
    #pragma unroll
    for (int db = 0; db < 4; ++db) {
        #pragma unroll
        for (int r = 0; r < 4; ++r) {
            const int s_ = qbw + lg*4 + r;
            attn[((size_t)(b*SEQ + s_))*D_MODEL + h*64 + db*16 + lr] = o[db][r] / l_run[r];
        }
    }
}

extern "C" void kernel_launch(void* const* d_in, const int* in_sizes, int n_in,
                              void* d_out, int out_size, void* d_ws, size_t ws_size,
                              hipStream_t stream)
{
    const float* q   = (const float*)d_in[0];
    const float* k   = (const float*)d_in[1];
    const float* v   = (const float*)d_in[2];
    // d_in[3] = mask (causal tril) — computed analytically in-kernel
    const float* w_q = (const float*)d_in[4];
    const float* b_q = (const float*)d_in[5];
    const float* w_k = (const float*)d_in[6];
    const float* b_k = (const float*)d_in[7];
    const float* w_v = (const float*)d_in[8];
    const float* b_v = (const float*)d_in[9];
    const float* w_o = (const float*)d_in[10];
    const float* b_o = (const float*)d_in[11];

    char* ws = (char*)d_ws;
    u16*   Qh  = (u16*)(ws);                               //  8 MiB bf16 (B,H,S,dk)
    u16*   Kh  = (u16*)(ws + (size_t)8*1024*1024);         //  8 MiB (B,H,S,dk)
    u16*   Vt  = (u16*)(ws + (size_t)16*1024*1024);        //  8 MiB (B,H,dk,S)
    float* att = (float*)(ws + (size_t)24*1024*1024);      // 16 MiB fp32 (B,S,D)

    const int M = BATCH * SEQ, N = D_MODEL, K = D_MODEL;
    dim3 gg(M/64, N/64);
    // Q projection carries the 1/sqrt(dk)=0.125 score scale (exact in bf16)
    gemm_bias_kernel<1><<<gg, 256, 0, stream>>>(q, w_q, b_q, 0.125f, Qh, M, N, K);
    gemm_bias_kernel<1><<<gg, 256, 0, stream>>>(k, w_k, b_k, 1.0f,   Kh, M, N, K);
    gemm_bias_kernel<2><<<gg, 256, 0, stream>>>(v, w_v, b_v, 1.0f,   Vt, M, N, K);
    flash_attn_kernel<<<dim3(SEQ/64, BATCH*N_HEADS), 256, 0, stream>>>(Qh, Kh, Vt, att);
    gemm_bias_kernel<0><<<gg, 256, 0, stream>>>(att, w_o, b_o, 1.0f, d_out, M, N, K);
}

// Round 3
// 257.544 us; speedup vs baseline: 1.3958x; 1.3958x over previous
//
#include <hip/hip_runtime.h>
#include <math.h>

#define D_MODEL 1024
#define N_HEADS 16
#define DKH     64
#define BATCH   2
#define SEQ     2048

typedef unsigned short u16;
typedef __attribute__((ext_vector_type(8))) short short8;
typedef __attribute__((ext_vector_type(4))) float f32x4;

__device__ __forceinline__ u16 f2bf(float f) {
    unsigned u = __float_as_uint(f);
    u += 0x7fffu + ((u >> 16) & 1u);
    return (u16)(u >> 16);
}

// C = X @ W^T + bias.  X:(M,K) fp32 row-major, W:(N,K) fp32 row-major.
// MODE 0: dst = fp32 (M,N) row-major, value = (acc+bias)*scale
// MODE 1: dst = bf16 scattered to (B, H, S, dk):  m=b*SEQ+s, n=h*64+d
// MODE 2: dst = bf16 scattered to (B, H, dk, S) [transposed, for PV staging]
template<int MODE>
__global__ __launch_bounds__(256)
void gemm_bias_kernel(const float* __restrict__ X, const float* __restrict__ W,
                      const float* __restrict__ bias, float scale,
                      void* __restrict__ dst, int M, int N, int K)
{
    __shared__ __align__(16) u16 As[64][40];   // 64 rows x 32 cols, +8 pad (80B stride)
    __shared__ __align__(16) u16 Bs[64][40];

    const int tid  = threadIdx.x;
    const int lane = tid & 63;
    const int wid  = tid >> 6;          // 4 waves: 2x2 over the 64x64 tile
    const int wm   = wid >> 1, wn = wid & 1;
    const int lr   = lane & 15, lg = lane >> 4;
    const int mb   = blockIdx.x * 64, nb = blockIdx.y * 64;

    const int srow = tid >> 2;          // staging: 0..63
    const int scol = (tid & 3) << 3;    // 0,8,16,24

    f32x4 acc00 = {0.f,0.f,0.f,0.f};
    f32x4 acc01 = acc00, acc10 = acc00, acc11 = acc00;

    const float* xrow = X + (size_t)(mb + srow) * K + scol;
    const float* wrow = W + (size_t)(nb + srow) * K + scol;

    for (int kt = 0; kt < K; kt += 32) {
        __syncthreads();
        float4 x0 = *(const float4*)(xrow + kt);
        float4 x1 = *(const float4*)(xrow + kt + 4);
        short8 av;
        av[0]=(short)f2bf(x0.x); av[1]=(short)f2bf(x0.y); av[2]=(short)f2bf(x0.z); av[3]=(short)f2bf(x0.w);
        av[4]=(short)f2bf(x1.x); av[5]=(short)f2bf(x1.y); av[6]=(short)f2bf(x1.z); av[7]=(short)f2bf(x1.w);
        *(short8*)&As[srow][scol] = av;
        float4 w0 = *(const float4*)(wrow + kt);
        float4 w1 = *(const float4*)(wrow + kt + 4);
        short8 bvv;
        bvv[0]=(short)f2bf(w0.x); bvv[1]=(short)f2bf(w0.y); bvv[2]=(short)f2bf(w0.z); bvv[3]=(short)f2bf(w0.w);
        bvv[4]=(short)f2bf(w1.x); bvv[5]=(short)f2bf(w1.y); bvv[6]=(short)f2bf(w1.z); bvv[7]=(short)f2bf(w1.w);
        *(short8*)&Bs[srow][scol] = bvv;
        __syncthreads();

        short8 a0 = *(short8*)&As[wm*32 +  0 + lr][lg*8];
        short8 a1 = *(short8*)&As[wm*32 + 16 + lr][lg*8];
        short8 b0 = *(short8*)&Bs[wn*32 +  0 + lr][lg*8];
        short8 b1 = *(short8*)&Bs[wn*32 + 16 + lr][lg*8];
        acc00 = __builtin_amdgcn_mfma_f32_16x16x32_bf16(a0, b0, acc00, 0, 0, 0);
        acc01 = __builtin_amdgcn_mfma_f32_16x16x32_bf16(a0, b1, acc01, 0, 0, 0);
        acc10 = __builtin_amdgcn_mfma_f32_16x16x32_bf16(a1, b0, acc10, 0, 0, 0);
        acc11 = __builtin_amdgcn_mfma_f32_16x16x32_bf16(a1, b1, acc11, 0, 0, 0);
    }

    // epilogue
    #pragma unroll
    for (int i = 0; i < 2; ++i) {
        #pragma unroll
        for (int j = 0; j < 2; ++j) {
            f32x4 a = (i==0) ? (j==0 ? acc00 : acc01) : (j==0 ? acc10 : acc11);
            const int mbase = mb + wm*32 + i*16 + lg*4;
            const int n     = nb + wn*32 + j*16 + lr;
            const float bn  = bias[n];
            #pragma unroll
            for (int r = 0; r < 4; ++r) {
                const int m = mbase + r;
                const float val = (a[r] + bn) * scale;
                if (MODE == 0) {
                    ((float*)dst)[(size_t)m * N + n] = val;
                } else if (MODE == 1) {
                    const int b = m >> 11, s = m & (SEQ - 1);
                    const int h = n >> 6,  d = n & 63;
                    ((u16*)dst)[(((size_t)(b*N_HEADS + h))*SEQ + s)*DKH + d] = f2bf(val);
                } else {
                    const int b = m >> 11, s = m & (SEQ - 1);
                    const int h = n >> 6,  d = n & 63;
                    ((u16*)dst)[(((size_t)(b*N_HEADS + h))*DKH + d)*SEQ + s] = f2bf(val);
                }
            }
        }
    }
}

// Flash attention, causal. Qh/Kh: (B*H, S, 64) bf16 (Q pre-scaled by 1/8).
// Vt: (B*H, 64, S) bf16 (transposed).  attn out: (B, S, D_MODEL) fp32.
// Block = 4 waves = 64 q rows; K/V kv-tiles (64 wide) staged cooperatively in
// LDS, double-buffered, XOR-swizzled (elem ^= (row&7)<<3) for conflict-free
// ds_read_b128 fragment reads.
__global__ __launch_bounds__(256)
void flash_attn_kernel(const u16* __restrict__ Qh, const u16* __restrict__ Kh,
                       const u16* __restrict__ Vt, float* __restrict__ attn)
{
    __shared__ __align__(16) u16 Kl[2][64][64];
    __shared__ __align__(16) u16 Vl[2][64][64];
    __shared__ __align__(16) u16 P[4][16][72];

    const int tid  = threadIdx.x;
    const int lane = tid & 63;
    const int wid  = tid >> 6;
    const int lr   = lane & 15, lg = lane >> 4;
    const int qt   = blockIdx.x;            // q tile of 64
    const int bh   = blockIdx.y;            // b*H + h
    const int qbw  = qt*64 + wid*16;        // wave's first q row
    const size_t base = (size_t)bh * SEQ * DKH;   // same for (S,64) and (64,S)

    // staging geometry: thread covers rows {srow, srow+32}, 8 elems at se0
    const int srow = tid >> 3;              // 0..31
    const int se0  = (tid & 7) << 3;        // 0..56
    const int ssw  = (srow & 7) << 3;       // XOR swizzle (row&7 same for +32)
    const int sec  = se0 ^ ssw;             // swizzled column

    // Q fragments (16 rows x 64 d) held in registers
    short8 aq0 = *(const short8*)&Qh[base + (size_t)(qbw + lr)*DKH +  0 + lg*8];
    short8 aq1 = *(const short8*)&Qh[base + (size_t)(qbw + lr)*DKH + 32 + lg*8];

    f32x4 o[4];
    float m_run[4], l_run[4];
    #pragma unroll
    for (int r = 0; r < 4; ++r) { m_run[r] = -INFINITY; l_run[r] = 0.f; }
    #pragma unroll
    for (int db = 0; db < 4; ++db) { f32x4 z = {0.f,0.f,0.f,0.f}; o[db] = z; }

    const int nc = qt + 1;                  // kv tiles of 64 needed (causal)

    // prologue: stage tile 0 into buffer 0
    {
        short8 k0 = *(const short8*)&Kh[base + (size_t)(srow     )*DKH + se0];
        short8 k1 = *(const short8*)&Kh[base + (size_t)(srow + 32)*DKH + se0];
        short8 v0 = *(const short8*)&Vt[base + (size_t)(srow     )*SEQ + se0];
        short8 v1 = *(const short8*)&Vt[base + (size_t)(srow + 32)*SEQ + se0];
        *(short8*)&Kl[0][srow     ][sec] = k0;
        *(short8*)&Kl[0][srow + 32][sec] = k1;
        *(short8*)&Vl[0][srow     ][sec] = v0;
        *(short8*)&Vl[0][srow + 32][sec] = v1;
    }
    __syncthreads();

    int cur = 0;
    for (int c = 0; c < nc; ++c) {
        const int kvb = c * 64;

        // issue next tile's global loads early (hide latency under compute)
        short8 nk0, nk1, nv0, nv1;
        const bool pref = (c + 1 < nc);
        if (pref) {
            const int nb_ = kvb + 64;
            nk0 = *(const short8*)&Kh[base + (size_t)(nb_ + srow     )*DKH + se0];
            nk1 = *(const short8*)&Kh[base + (size_t)(nb_ + srow + 32)*DKH + se0];
            nv0 = *(const short8*)&Vt[base + (size_t)(srow     )*SEQ + nb_ + se0];
            nv1 = *(const short8*)&Vt[base + (size_t)(srow + 32)*SEQ + nb_ + se0];
        }

        // S = Q K^T  (16 q x 64 kv), four 16-col blocks from swizzled LDS
        f32x4 s[4];
        const int ksw = (lr & 7) << 3;
        #pragma unroll
        for (int cb = 0; cb < 4; ++cb) {
            const int kr = cb*16 + lr;
            f32x4 z = {0.f,0.f,0.f,0.f};
            short8 k0 = *(short8*)&Kl[cur][kr][( 0 + lg*8) ^ ksw];
            short8 k1 = *(short8*)&Kl[cur][kr][(32 + lg*8) ^ ksw];
            z = __builtin_amdgcn_mfma_f32_16x16x32_bf16(aq0, k0, z, 0, 0, 0);
            z = __builtin_amdgcn_mfma_f32_16x16x32_bf16(aq1, k1, z, 0, 0, 0);
            s[cb] = z;
        }

        // causal mask (only relevant for the trailing tile)
        if (kvb + 63 > qbw) {
            #pragma unroll
            for (int cb = 0; cb < 4; ++cb)
                #pragma unroll
                for (int r = 0; r < 4; ++r)
                    if (kvb + cb*16 + lr > qbw + lg*4 + r) s[cb][r] = -INFINITY;
        }

        // online softmax (row = lg*4+r spread across 16-lane group lr)
        float alpha[4];
        #pragma unroll
        for (int r = 0; r < 4; ++r) {
            float tm = fmaxf(fmaxf(s[0][r], s[1][r]), fmaxf(s[2][r], s[3][r]));
            #pragma unroll
            for (int off = 1; off < 16; off <<= 1) tm = fmaxf(tm, __shfl_xor(tm, off));
            const float mnew = fmaxf(m_run[r], tm);
            alpha[r] = __expf(m_run[r] - mnew);     // m_run=-inf -> 0
            float ts = 0.f;
            #pragma unroll
            for (int cb = 0; cb < 4; ++cb) {
                const float p = __expf(s[cb][r] - mnew);
                P[wid][lg*4 + r][cb*16 + lr] = f2bf(p);
                ts += p;
            }
            #pragma unroll
            for (int off = 1; off < 16; off <<= 1) ts += __shfl_xor(ts, off);
            l_run[r] = l_run[r]*alpha[r] + ts;
            m_run[r] = mnew;
        }
        #pragma unroll
        for (int db = 0; db < 4; ++db)
            #pragma unroll
            for (int r = 0; r < 4; ++r) o[db][r] *= alpha[r];

        // O += P @ V   (two k-slices of 32, V fragments from swizzled LDS)
        #pragma unroll
        for (int ks = 0; ks < 2; ++ks) {
            short8 ap = *(short8*)&P[wid][lr][ks*32 + lg*8];
            #pragma unroll
            for (int db = 0; db < 4; ++db) {
                const int vr = db*16 + lr;
                short8 bv = *(short8*)&Vl[cur][vr][(ks*32 + lg*8) ^ ksw];
                o[db] = __builtin_amdgcn_mfma_f32_16x16x32_bf16(ap, bv, o[db], 0, 0, 0);
            }
        }

        __syncthreads();                 // all waves done reading buf[cur^1] (last iter)
        if (pref) {
            *(short8*)&Kl[cur^1][srow     ][sec] = nk0;
            *(short8*)&Kl[cur^1][srow + 32][sec] = nk1;
            *(short8*)&Vl[cur^1][srow     ][sec] = nv0;
            *(short8*)&Vl[cur^1][srow + 32][sec] = nv1;
        }
        __syncthreads();                 // next tile staged
        cur ^= 1;
    }

    const int b = bh >> 4, h = bh & 15;
    #pragma unroll
    for (int db = 0; db < 4; ++db) {
        #pragma unroll
        for (int r = 0; r < 4; ++r) {
            const int s_ = qbw + lg*4 + r;
            attn[((size_t)(b*SEQ + s_))*D_MODEL + h*64 + db*16 + lr] = o[db][r] / l_run[r];
        }
    }
}

extern "C" void kernel_launch(void* const* d_in, const int* in_sizes, int n_in,
                              void* d_out, int out_size, void* d_ws, size_t ws_size,
                              hipStream_t stream)
{
    const float* q   = (const float*)d_in[0];
    const float* k   = (const float*)d_in[1];
    const float* v   = (const float*)d_in[2];
    // d_in[3] = mask (causal tril) — computed analytically in-kernel
    const float* w_q = (const float*)d_in[4];
    const float* b_q = (const float*)d_in[5];
    const float* w_k = (const float*)d_in[6];
    const float* b_k = (const float*)d_in[7];
    const float* w_v = (const float*)d_in[8];
    const float* b_v = (const float*)d_in[9];
    const float* w_o = (const float*)d_in[10];
    const float* b_o = (const float*)d_in[11];

    char* ws = (char*)d_ws;
    u16*   Qh  = (u16*)(ws);                               //  8 MiB bf16 (B,H,S,dk)
    u16*   Kh  = (u16*)(ws + (size_t)8*1024*1024);         //  8 MiB (B,H,S,dk)
    u16*   Vt  = (u16*)(ws + (size_t)16*1024*1024);        //  8 MiB (B,H,dk,S)
    float* att = (float*)(ws + (size_t)24*1024*1024);      // 16 MiB fp32 (B,S,D)

    const int M = BATCH * SEQ, N = D_MODEL, K = D_MODEL;
    dim3 gg(M/64, N/64);
    // Q projection carries the 1/sqrt(dk)=0.125 score scale (exact in bf16)
    gemm_bias_kernel<1><<<gg, 256, 0, stream>>>(q, w_q, b_q, 0.125f, Qh, M, N, K);
    gemm_bias_kernel<1><<<gg, 256, 0, stream>>>(k, w_k, b_k, 1.0f,   Kh, M, N, K);
    gemm_bias_kernel<2><<<gg, 256, 0, stream>>>(v, w_v, b_v, 1.0f,   Vt, M, N, K);
    flash_attn_kernel<<<dim3(SEQ/64, BATCH*N_HEADS), 256, 0, stream>>>(Qh, Kh, Vt, att);
    gemm_bias_kernel<0><<<gg, 256, 0, stream>>>(att, w_o, b_o, 1.0f, d_out, M, N, K);
}

// Round 4
// 214.067 us; speedup vs baseline: 1.6793x; 1.2031x over previous
//
#include <hip/hip_runtime.h>
#include <math.h>

#define D_MODEL 1024
#define N_HEADS 16
#define DKH     64
#define BATCH   2
#define SEQ     2048
#define NT      (SEQ/64)          // 32 q-tiles of 64

typedef unsigned short u16;
typedef __attribute__((ext_vector_type(8))) short short8;
typedef __attribute__((ext_vector_type(4))) float f32x4;

__device__ __forceinline__ u16 f2bf(float f) {
    unsigned u = __float_as_uint(f);
    u += 0x7fffu + ((u >> 16) & 1u);
    return (u16)(u >> 16);
}

// C = X @ W^T + bias.  X:(M,K) fp32 row-major, W:(N,K) fp32 row-major.
// 128x128 tile, 4 waves (2x2 quadrants of 64x64), 4x4 16x16x32 MFMA accum.
// Double-buffered LDS; global loads issued before compute, convert+ds_write
// after the barrier (latency hides under MFMA).
// MODE 0: dst fp32 (M,N) = (acc+bias)*scale
// MODE 1: dst bf16 (B,H,S,dk)
// MODE 2: dst bf16 (B,H,dk,S)
template<int MODE>
__global__ __launch_bounds__(256)
void gemm_bias_kernel(const float* __restrict__ X, const float* __restrict__ W,
                      const float* __restrict__ bias, float scale,
                      void* __restrict__ dst, int M, int N, int K)
{
    __shared__ __align__(16) u16 As[2][128][40];   // 128 rows x 32 K-cols (+8 pad)
    __shared__ __align__(16) u16 Bs[2][128][40];

    const int tid  = threadIdx.x;
    const int lane = tid & 63;
    const int wid  = tid >> 6;
    const int wm   = wid >> 1, wn = wid & 1;
    const int lr   = lane & 15, lg = lane >> 4;
    const int mb   = blockIdx.x * 128, nb = blockIdx.y * 128;

    const int srow = tid >> 1;            // 0..127
    const int scol = (tid & 1) * 16;      // f32/u16 col offset: 0 or 16

    const float* xp = X + (size_t)(mb + srow) * K + scol;
    const float* wp = W + (size_t)(nb + srow) * K + scol;

    f32x4 acc[4][4];
    #pragma unroll
    for (int i = 0; i < 4; ++i)
        #pragma unroll
        for (int j = 0; j < 4; ++j) { f32x4 z = {0.f,0.f,0.f,0.f}; acc[i][j] = z; }

    // prologue: stage K-tile 0 into buffer 0
    {
        float4 x0 = *(const float4*)(xp+0), x1 = *(const float4*)(xp+4);
        float4 x2 = *(const float4*)(xp+8), x3 = *(const float4*)(xp+12);
        float4 w0 = *(const float4*)(wp+0), w1 = *(const float4*)(wp+4);
        float4 w2 = *(const float4*)(wp+8), w3 = *(const float4*)(wp+12);
        short8 a0, a1, b0, b1;
        a0[0]=(short)f2bf(x0.x); a0[1]=(short)f2bf(x0.y); a0[2]=(short)f2bf(x0.z); a0[3]=(short)f2bf(x0.w);
        a0[4]=(short)f2bf(x1.x); a0[5]=(short)f2bf(x1.y); a0[6]=(short)f2bf(x1.z); a0[7]=(short)f2bf(x1.w);
        a1[0]=(short)f2bf(x2.x); a1[1]=(short)f2bf(x2.y); a1[2]=(short)f2bf(x2.z); a1[3]=(short)f2bf(x2.w);
        a1[4]=(short)f2bf(x3.x); a1[5]=(short)f2bf(x3.y); a1[6]=(short)f2bf(x3.z); a1[7]=(short)f2bf(x3.w);
        b0[0]=(short)f2bf(w0.x); b0[1]=(short)f2bf(w0.y); b0[2]=(short)f2bf(w0.z); b0[3]=(short)f2bf(w0.w);
        b0[4]=(short)f2bf(w1.x); b0[5]=(short)f2bf(w1.y); b0[6]=(short)f2bf(w1.z); b0[7]=(short)f2bf(w1.w);
        b1[0]=(short)f2bf(w2.x); b1[1]=(short)f2bf(w2.y); b1[2]=(short)f2bf(w2.z); b1[3]=(short)f2bf(w2.w);
        b1[4]=(short)f2bf(w3.x); b1[5]=(short)f2bf(w3.y); b1[6]=(short)f2bf(w3.z); b1[7]=(short)f2bf(w3.w);
        *(short8*)&As[0][srow][scol]     = a0;
        *(short8*)&As[0][srow][scol + 8] = a1;
        *(short8*)&Bs[0][srow][scol]     = b0;
        *(short8*)&Bs[0][srow][scol + 8] = b1;
    }
    __syncthreads();

    const int NK = K / 32;
    for (int it = 0; it < NK; ++it) {
        const int cur = it & 1;
        const bool pref = (it + 1 < NK);
        float4 x0,x1,x2,x3,w0,w1,w2,w3;
        if (pref) {
            const int kt = (it + 1) * 32;
            x0 = *(const float4*)(xp+kt+0);  x1 = *(const float4*)(xp+kt+4);
            x2 = *(const float4*)(xp+kt+8);  x3 = *(const float4*)(xp+kt+12);
            w0 = *(const float4*)(wp+kt+0);  w1 = *(const float4*)(wp+kt+4);
            w2 = *(const float4*)(wp+kt+8);  w3 = *(const float4*)(wp+kt+12);
        }

        short8 a[4], b[4];
        #pragma unroll
        for (int i = 0; i < 4; ++i) a[i] = *(short8*)&As[cur][wm*64 + i*16 + lr][lg*8];
        #pragma unroll
        for (int j = 0; j < 4; ++j) b[j] = *(short8*)&Bs[cur][wn*64 + j*16 + lr][lg*8];
        #pragma unroll
        for (int i = 0; i < 4; ++i)
            #pragma unroll
            for (int j = 0; j < 4; ++j)
                acc[i][j] = __builtin_amdgcn_mfma_f32_16x16x32_bf16(a[i], b[j], acc[i][j], 0, 0, 0);

        __syncthreads();
        if (pref) {
            short8 a0, a1, b0, b1;
            a0[0]=(short)f2bf(x0.x); a0[1]=(short)f2bf(x0.y); a0[2]=(short)f2bf(x0.z); a0[3]=(short)f2bf(x0.w);
            a0[4]=(short)f2bf(x1.x); a0[5]=(short)f2bf(x1.y); a0[6]=(short)f2bf(x1.z); a0[7]=(short)f2bf(x1.w);
            a1[0]=(short)f2bf(x2.x); a1[1]=(short)f2bf(x2.y); a1[2]=(short)f2bf(x2.z); a1[3]=(short)f2bf(x2.w);
            a1[4]=(short)f2bf(x3.x); a1[5]=(short)f2bf(x3.y); a1[6]=(short)f2bf(x3.z); a1[7]=(short)f2bf(x3.w);
            b0[0]=(short)f2bf(w0.x); b0[1]=(short)f2bf(w0.y); b0[2]=(short)f2bf(w0.z); b0[3]=(short)f2bf(w0.w);
            b0[4]=(short)f2bf(w1.x); b0[5]=(short)f2bf(w1.y); b0[6]=(short)f2bf(w1.z); b0[7]=(short)f2bf(w1.w);
            b1[0]=(short)f2bf(w2.x); b1[1]=(short)f2bf(w2.y); b1[2]=(short)f2bf(w2.z); b1[3]=(short)f2bf(w2.w);
            b1[4]=(short)f2bf(w3.x); b1[5]=(short)f2bf(w3.y); b1[6]=(short)f2bf(w3.z); b1[7]=(short)f2bf(w3.w);
            *(short8*)&As[cur^1][srow][scol]     = a0;
            *(short8*)&As[cur^1][srow][scol + 8] = a1;
            *(short8*)&Bs[cur^1][srow][scol]     = b0;
            *(short8*)&Bs[cur^1][srow][scol + 8] = b1;
        }
        __syncthreads();
    }

    // epilogue
    #pragma unroll
    for (int i = 0; i < 4; ++i) {
        #pragma unroll
        for (int j = 0; j < 4; ++j) {
            const int mbase = mb + wm*64 + i*16 + lg*4;
            const int n     = nb + wn*64 + j*16 + lr;
            const float bn  = bias[n];
            #pragma unroll
            for (int r = 0; r < 4; ++r) {
                const int m = mbase + r;
                const float val = (acc[i][j][r] + bn) * scale;
                if (MODE == 0) {
                    ((float*)dst)[(size_t)m * N + n] = val;
                } else if (MODE == 1) {
                    const int b = m >> 11, s = m & (SEQ - 1);
                    const int h = n >> 6,  d = n & 63;
                    ((u16*)dst)[(((size_t)(b*N_HEADS + h))*SEQ + s)*DKH + d] = f2bf(val);
                } else {
                    const int b = m >> 11, s = m & (SEQ - 1);
                    const int h = n >> 6,  d = n & 63;
                    ((u16*)dst)[(((size_t)(b*N_HEADS + h))*DKH + d)*SEQ + s] = f2bf(val);
                }
            }
        }
    }
}

// one attention step: 16 q rows x 64 kv, online softmax, O += P V
__device__ __forceinline__ void attn_step(
    const short8& aq0, const short8& aq1,
    f32x4 (&o)[4], float (&m_run)[4], float (&l_run)[4],
    const u16 (*__restrict__ Kl)[64], const u16 (*__restrict__ Vl)[64],
    u16 (*__restrict__ Pw)[72],
    int kvb, int qbw, int lr, int lg)
{
    const int ksw = (lr & 7) << 3;
    f32x4 s[4];
    #pragma unroll
    for (int cb = 0; cb < 4; ++cb) {
        const int kr = cb*16 + lr;
        f32x4 z = {0.f,0.f,0.f,0.f};
        short8 k0 = *(const short8*)&Kl[kr][( 0 + lg*8) ^ ksw];
        short8 k1 = *(const short8*)&Kl[kr][(32 + lg*8) ^ ksw];
        z = __builtin_amdgcn_mfma_f32_16x16x32_bf16(aq0, k0, z, 0, 0, 0);
        z = __builtin_amdgcn_mfma_f32_16x16x32_bf16(aq1, k1, z, 0, 0, 0);
        s[cb] = z;
    }

    if (kvb + 63 > qbw) {
        #pragma unroll
        for (int cb = 0; cb < 4; ++cb)
            #pragma unroll
            for (int r = 0; r < 4; ++r)
                if (kvb + cb*16 + lr > qbw + lg*4 + r) s[cb][r] = -INFINITY;
    }

    float alpha[4];
    #pragma unroll
    for (int r = 0; r < 4; ++r) {
        float tm = fmaxf(fmaxf(s[0][r], s[1][r]), fmaxf(s[2][r], s[3][r]));
        #pragma unroll
        for (int off = 1; off < 16; off <<= 1) tm = fmaxf(tm, __shfl_xor(tm, off));
        const float mnew = fmaxf(m_run[r], tm);
        alpha[r] = __expf(m_run[r] - mnew);
        float ts = 0.f;
        #pragma unroll
        for (int cb = 0; cb < 4; ++cb) {
            const float p = __expf(s[cb][r] - mnew);
            Pw[lg*4 + r][cb*16 + lr] = f2bf(p);
            ts += p;
        }
        #pragma unroll
        for (int off = 1; off < 16; off <<= 1) ts += __shfl_xor(ts, off);
        l_run[r] = l_run[r]*alpha[r] + ts;
        m_run[r] = mnew;
    }
    #pragma unroll
    for (int db = 0; db < 4; ++db)
        #pragma unroll
        for (int r = 0; r < 4; ++r) o[db][r] *= alpha[r];

    #pragma unroll
    for (int ks = 0; ks < 2; ++ks) {
        short8 ap = *(short8*)&Pw[lr][ks*32 + lg*8];
        #pragma unroll
        for (int db = 0; db < 4; ++db) {
            const int vr = db*16 + lr;
            short8 bv = *(const short8*)&Vl[vr][(ks*32 + lg*8) ^ ksw];
            o[db] = __builtin_amdgcn_mfma_f32_16x16x32_bf16(ap, bv, o[db], 0, 0, 0);
        }
    }
}

// Flash attention, causal, work-balanced: block handles q-tiles (qtl, 31-qtl)
// over one shared kv stream -> every block does exactly 33 compute-steps.
__global__ __launch_bounds__(256)
void flash_attn_kernel(const u16* __restrict__ Qh, const u16* __restrict__ Kh,
                       const u16* __restrict__ Vt, float* __restrict__ attn)
{
    __shared__ __align__(16) u16 Kl[2][64][64];
    __shared__ __align__(16) u16 Vl[2][64][64];
    __shared__ __align__(16) u16 P[4][16][72];

    const int tid  = threadIdx.x;
    const int lane = tid & 63;
    const int wid  = tid >> 6;
    const int lr   = lane & 15, lg = lane >> 4;
    const int qtl  = blockIdx.x;            // 0..15
    const int bh   = blockIdx.y;            // b*H + h
    const int qlo  = qtl, qhi = NT - 1 - qtl;
    const int qbw_lo = qlo*64 + wid*16;
    const int qbw_hi = qhi*64 + wid*16;
    const size_t base = (size_t)bh * SEQ * DKH;

    const int srow = tid >> 3;              // 0..31
    const int se0  = (tid & 7) << 3;        // 0..56
    const int sec  = se0 ^ ((srow & 7) << 3);

    short8 aqlo0 = *(const short8*)&Qh[base + (size_t)(qbw_lo + lr)*DKH +  0 + lg*8];
    short8 aqlo1 = *(const short8*)&Qh[base + (size_t)(qbw_lo + lr)*DKH + 32 + lg*8];
    short8 aqhi0 = *(const short8*)&Qh[base + (size_t)(qbw_hi + lr)*DKH +  0 + lg*8];
    short8 aqhi1 = *(const short8*)&Qh[base + (size_t)(qbw_hi + lr)*DKH + 32 + lg*8];

    f32x4 o_lo[4], o_hi[4];
    float m_lo[4], l_lo[4], m_hi[4], l_hi[4];
    #pragma unroll
    for (int r = 0; r < 4; ++r) { m_lo[r] = -INFINITY; l_lo[r] = 0.f; m_hi[r] = -INFINITY; l_hi[r] = 0.f; }
    #pragma unroll
    for (int db = 0; db < 4; ++db) { f32x4 z = {0.f,0.f,0.f,0.f}; o_lo[db] = z; o_hi[db] = z; }

    const int nc = qhi + 1;

    {
        short8 k0 = *(const short8*)&Kh[base + (size_t)(srow     )*DKH + se0];
        short8 k1 = *(const short8*)&Kh[base + (size_t)(srow + 32)*DKH + se0];
        short8 v0 = *(const short8*)&Vt[base + (size_t)(srow     )*SEQ + se0];
        short8 v1 = *(const short8*)&Vt[base + (size_t)(srow + 32)*SEQ + se0];
        *(short8*)&Kl[0][srow     ][sec] = k0;
        *(short8*)&Kl[0][srow + 32][sec] = k1;
        *(short8*)&Vl[0][srow     ][sec] = v0;
        *(short8*)&Vl[0][srow + 32][sec] = v1;
    }
    __syncthreads();

    int cur = 0;
    for (int c = 0; c < nc; ++c) {
        const int kvb = c * 64;
        short8 nk0, nk1, nv0, nv1;
        const bool pref = (c + 1 < nc);
        if (pref) {
            const int nb_ = kvb + 64;
            nk0 = *(const short8*)&Kh[base + (size_t)(nb_ + srow     )*DKH + se0];
            nk1 = *(const short8*)&Kh[base + (size_t)(nb_ + srow + 32)*DKH + se0];
            nv0 = *(const short8*)&Vt[base + (size_t)(srow     )*SEQ + nb_ + se0];
            nv1 = *(const short8*)&Vt[base + (size_t)(srow + 32)*SEQ + nb_ + se0];
        }

        attn_step(aqhi0, aqhi1, o_hi, m_hi, l_hi, Kl[cur], Vl[cur], P[wid], kvb, qbw_hi, lr, lg);
        if (c <= qlo)
            attn_step(aqlo0, aqlo1, o_lo, m_lo, l_lo, Kl[cur], Vl[cur], P[wid], kvb, qbw_lo, lr, lg);

        __syncthreads();
        if (pref) {
            *(short8*)&Kl[cur^1][srow     ][sec] = nk0;
            *(short8*)&Kl[cur^1][srow + 32][sec] = nk1;
            *(short8*)&Vl[cur^1][srow     ][sec] = nv0;
            *(short8*)&Vl[cur^1][srow + 32][sec] = nv1;
        }
        __syncthreads();
        cur ^= 1;
    }

    const int b = bh >> 4, h = bh & 15;
    #pragma unroll
    for (int db = 0; db < 4; ++db) {
        #pragma unroll
        for (int r = 0; r < 4; ++r) {
            const int slo = qbw_lo + lg*4 + r;
            const int shi = qbw_hi + lg*4 + r;
            attn[((size_t)(b*SEQ + slo))*D_MODEL + h*64 + db*16 + lr] = o_lo[db][r] / l_lo[r];
            attn[((size_t)(b*SEQ + shi))*D_MODEL + h*64 + db*16 + lr] = o_hi[db][r] / l_hi[r];
        }
    }
}

extern "C" void kernel_launch(void* const* d_in, const int* in_sizes, int n_in,
                              void* d_out, int out_size, void* d_ws, size_t ws_size,
                              hipStream_t stream)
{
    const float* q   = (const float*)d_in[0];
    const float* k   = (const float*)d_in[1];
    const float* v   = (const float*)d_in[2];
    // d_in[3] = mask (causal tril) — computed analytically in-kernel
    const float* w_q = (const float*)d_in[4];
    const float* b_q = (const float*)d_in[5];
    const float* w_k = (const float*)d_in[6];
    const float* b_k = (const float*)d_in[7];
    const float* w_v = (const float*)d_in[8];
    const float* b_v = (const float*)d_in[9];
    const float* w_o = (const float*)d_in[10];
    const float* b_o = (const float*)d_in[11];

    char* ws = (char*)d_ws;
    u16*   Qh  = (u16*)(ws);                               //  8 MiB bf16 (B,H,S,dk)
    u16*   Kh  = (u16*)(ws + (size_t)8*1024*1024);         //  8 MiB (B,H,S,dk)
    u16*   Vt  = (u16*)(ws + (size_t)16*1024*1024);        //  8 MiB (B,H,dk,S)
    float* att = (float*)(ws + (size_t)24*1024*1024);      // 16 MiB fp32 (B,S,D)

    const int M = BATCH * SEQ, N = D_MODEL, K = D_MODEL;
    dim3 gg(M/128, N/128);
    // Q projection carries the 1/sqrt(dk)=0.125 score scale (exact in bf16)
    gemm_bias_kernel<1><<<gg, 256, 0, stream>>>(q, w_q, b_q, 0.125f, Qh, M, N, K);
    gemm_bias_kernel<1><<<gg, 256, 0, stream>>>(k, w_k, b_k, 1.0f,   Kh, M, N, K);
    gemm_bias_kernel<2><<<gg, 256, 0, stream>>>(v, w_v, b_v, 1.0f,   Vt, M, N, K);
    flash_attn_kernel<<<dim3(NT/2, BATCH*N_HEADS), 256, 0, stream>>>(Qh, Kh, Vt, att);
    gemm_bias_kernel<0><<<gg, 256, 0, stream>>>(att, w_o, b_o, 1.0f, d_out, M, N, K);
}

// Round 5
// 184.148 us; speedup vs baseline: 1.9521x; 1.1625x over previous
//
#include <hip/hip_runtime.h>
#include <math.h>

#define D_MODEL 1024
#define N_HEADS 16
#define DKH     64
#define BATCH   2
#define SEQ     2048
#define NT      (SEQ/64)          // 32 q-tiles of 64

typedef unsigned short u16;
typedef __attribute__((ext_vector_type(8))) short short8;
typedef __attribute__((ext_vector_type(4))) float f32x4;

__device__ __forceinline__ u16 f2bf(float f) {
    unsigned u = __float_as_uint(f);
    u += 0x7fffu + ((u >> 16) & 1u);
    return (u16)(u >> 16);
}

__device__ __forceinline__ void gll16(const void* g, void* l) {
    __builtin_amdgcn_global_load_lds((const __attribute__((address_space(1))) void*)g,
                                     (__attribute__((address_space(3))) void*)l, 16, 0, 0);
}

// ---------------------------------------------------------------------------
// fp32 -> bf16 convert: q,k,v (4M elems each) + w_q,w_k,w_v,w_o (1M each)
// ---------------------------------------------------------------------------
__global__ __launch_bounds__(256)
void convert_kernel(const float* __restrict__ q, const float* __restrict__ k,
                    const float* __restrict__ v, const float* __restrict__ wq,
                    const float* __restrict__ wk, const float* __restrict__ wv,
                    const float* __restrict__ wo,
                    u16* __restrict__ qb, u16* __restrict__ kb, u16* __restrict__ vb,
                    u16* __restrict__ wqb, u16* __restrict__ wkb,
                    u16* __restrict__ wvb, u16* __restrict__ wob)
{
    const size_t NV = ((size_t)16 << 20) >> 3;   // total 16M elems in vec8 units
    for (size_t i = (size_t)blockIdx.x * blockDim.x + threadIdx.x; i < NV;
         i += (size_t)gridDim.x * blockDim.x) {
        const size_t e = i << 3;
        const float* s; u16* d; size_t off;
        if (e < ((size_t)12 << 20)) {
            const int seg = (int)(e >> 22);
            off = e & (((size_t)1 << 22) - 1);
            s = seg == 0 ? q : seg == 1 ? k : v;
            d = seg == 0 ? qb : seg == 1 ? kb : vb;
        } else {
            const size_t r = e - ((size_t)12 << 20);
            const int seg = (int)(r >> 20);
            off = r & (((size_t)1 << 20) - 1);
            s = seg == 0 ? wq : seg == 1 ? wk : seg == 2 ? wv : wo;
            d = seg == 0 ? wqb : seg == 1 ? wkb : seg == 2 ? wvb : wob;
        }
        const float4 f0 = *(const float4*)(s + off);
        const float4 f1 = *(const float4*)(s + off + 4);
        short8 o;
        o[0]=(short)f2bf(f0.x); o[1]=(short)f2bf(f0.y); o[2]=(short)f2bf(f0.z); o[3]=(short)f2bf(f0.w);
        o[4]=(short)f2bf(f1.x); o[5]=(short)f2bf(f1.y); o[6]=(short)f2bf(f1.z); o[7]=(short)f2bf(f1.w);
        *(short8*)(d + off) = o;
    }
}

// ---------------------------------------------------------------------------
// Pure-bf16 GEMM: C = A @ B^T + bias.  A:(M,K) bf16 row-major, B:(N,K) bf16.
// 128x128 tile, BK=32, 4 waves (2x2 quadrants), global_load_lds staging into
// linear [128][32] LDS (lane order == linear layout; frag ds_read_b128 reads
// 1KB contiguous per wave -> conflict-free). One barrier per K-step; next
// tile's loads are issued before compute and drain at the barrier.
// MODE 0: dst fp32 (M,N) = (acc+bias)*scale
// MODE 1: dst bf16 (B,H,S,dk)
// MODE 2: dst bf16 (B,H,dk,S)
// ---------------------------------------------------------------------------
template<int MODE>
__global__ __launch_bounds__(256)
void gemm_bf16_kernel(const u16* __restrict__ A, const u16* __restrict__ Bw,
                      const float* __restrict__ bias, float scale,
                      void* __restrict__ dst, int M, int N, int K)
{
    __shared__ __align__(16) u16 As[2][128][32];
    __shared__ __align__(16) u16 Bs[2][128][32];

    const int tid  = threadIdx.x;
    const int lane = tid & 63;
    const int wid  = tid >> 6;
    const int wm   = wid >> 1, wn = wid & 1;
    const int lr   = lane & 15, lg = lane >> 4;
    const int mb   = blockIdx.x * 128, nb = blockIdx.y * 128;

    const int g_row = lane >> 2;          // lane's row within a 16-row group
    const int g_col = (lane & 3) << 3;    // lane's elem offset (8 bf16 = 16B)

    const u16* Ab = A  + (size_t)mb * K;
    const u16* Bb = Bw + (size_t)nb * K;

    f32x4 acc[4][4];
    #pragma unroll
    for (int i = 0; i < 4; ++i)
        #pragma unroll
        for (int j = 0; j < 4; ++j) { f32x4 z = {0.f,0.f,0.f,0.f}; acc[i][j] = z; }

    // stage K-tile kt into buffer buf (4 global_load_lds per thread)
#define STAGE(buf, kt)                                                          \
    {                                                                           \
        _Pragma("unroll")                                                       \
        for (int t = 0; t < 2; ++t) {                                           \
            const int r0 = t*64 + wid*16;                                       \
            gll16(&Ab[(size_t)(r0 + g_row)*K + (kt) + g_col], &As[buf][r0][0]); \
            gll16(&Bb[(size_t)(r0 + g_row)*K + (kt) + g_col], &Bs[buf][r0][0]); \
        }                                                                       \
    }

    STAGE(0, 0)
    __syncthreads();

    const int NK = K >> 5;
    for (int it = 0; it < NK; ++it) {
        const int c = it & 1;
        if (it + 1 < NK) STAGE(c ^ 1, (it + 1) << 5)

        short8 a[4], b[4];
        #pragma unroll
        for (int i = 0; i < 4; ++i) a[i] = *(const short8*)&As[c][wm*64 + i*16 + lr][lg*8];
        #pragma unroll
        for (int j = 0; j < 4; ++j) b[j] = *(const short8*)&Bs[c][wn*64 + j*16 + lr][lg*8];
        #pragma unroll
        for (int i = 0; i < 4; ++i)
            #pragma unroll
            for (int j = 0; j < 4; ++j)
                acc[i][j] = __builtin_amdgcn_mfma_f32_16x16x32_bf16(a[i], b[j], acc[i][j], 0, 0, 0);

        __syncthreads();   // drains this iter's reads AND next tile's loads
    }
#undef STAGE

    // epilogue
    #pragma unroll
    for (int i = 0; i < 4; ++i) {
        #pragma unroll
        for (int j = 0; j < 4; ++j) {
            const int mbase = mb + wm*64 + i*16 + lg*4;
            const int n     = nb + wn*64 + j*16 + lr;
            const float bn  = bias[n];
            #pragma unroll
            for (int r = 0; r < 4; ++r) {
                const int m = mbase + r;
                const float val = (acc[i][j][r] + bn) * scale;
                if (MODE == 0) {
                    ((float*)dst)[(size_t)m * N + n] = val;
                } else if (MODE == 1) {
                    const int b = m >> 11, s = m & (SEQ - 1);
                    const int h = n >> 6,  d = n & 63;
                    ((u16*)dst)[(((size_t)(b*N_HEADS + h))*SEQ + s)*DKH + d] = f2bf(val);
                } else {
                    const int b = m >> 11, s = m & (SEQ - 1);
                    const int h = n >> 6,  d = n & 63;
                    ((u16*)dst)[(((size_t)(b*N_HEADS + h))*DKH + d)*SEQ + s] = f2bf(val);
                }
            }
        }
    }
}

// ---------------------------------------------------------------------------
// one attention step: 16 q rows x 64 kv, online softmax, O += P V
// ---------------------------------------------------------------------------
__device__ __forceinline__ void attn_step(
    const short8& aq0, const short8& aq1,
    f32x4 (&o)[4], float (&m_run)[4], float (&l_run)[4],
    const u16 (*__restrict__ Kl)[64], const u16 (*__restrict__ Vl)[64],
    u16 (*__restrict__ Pw)[72],
    int kvb, int qbw, int lr, int lg)
{
    const int ksw = (lr & 7) << 3;
    f32x4 s[4];
    #pragma unroll
    for (int cb = 0; cb < 4; ++cb) {
        const int kr = cb*16 + lr;
        f32x4 z = {0.f,0.f,0.f,0.f};
        short8 k0 = *(const short8*)&Kl[kr][( 0 + lg*8) ^ ksw];
        short8 k1 = *(const short8*)&Kl[kr][(32 + lg*8) ^ ksw];
        z = __builtin_amdgcn_mfma_f32_16x16x32_bf16(aq0, k0, z, 0, 0, 0);
        z = __builtin_amdgcn_mfma_f32_16x16x32_bf16(aq1, k1, z, 0, 0, 0);
        s[cb] = z;
    }

    if (kvb + 63 > qbw) {
        #pragma unroll
        for (int cb = 0; cb < 4; ++cb)
            #pragma unroll
            for (int r = 0; r < 4; ++r)
                if (kvb + cb*16 + lr > qbw + lg*4 + r) s[cb][r] = -INFINITY;
    }

    float alpha[4];
    #pragma unroll
    for (int r = 0; r < 4; ++r) {
        float tm = fmaxf(fmaxf(s[0][r], s[1][r]), fmaxf(s[2][r], s[3][r]));
        #pragma unroll
        for (int off = 1; off < 16; off <<= 1) tm = fmaxf(tm, __shfl_xor(tm, off));
        const float mnew = fmaxf(m_run[r], tm);
        alpha[r] = __expf(m_run[r] - mnew);
        float ts = 0.f;
        #pragma unroll
        for (int cb = 0; cb < 4; ++cb) {
            const float p = __expf(s[cb][r] - mnew);
            Pw[lg*4 + r][cb*16 + lr] = f2bf(p);
            ts += p;
        }
        #pragma unroll
        for (int off = 1; off < 16; off <<= 1) ts += __shfl_xor(ts, off);
        l_run[r] = l_run[r]*alpha[r] + ts;
        m_run[r] = mnew;
    }
    #pragma unroll
    for (int db = 0; db < 4; ++db)
        #pragma unroll
        for (int r = 0; r < 4; ++r) o[db][r] *= alpha[r];

    #pragma unroll
    for (int ks = 0; ks < 2; ++ks) {
        short8 ap = *(short8*)&Pw[lr][ks*32 + lg*8];
        #pragma unroll
        for (int db = 0; db < 4; ++db) {
            const int vr = db*16 + lr;
            short8 bv = *(const short8*)&Vl[vr][(ks*32 + lg*8) ^ ksw];
            o[db] = __builtin_amdgcn_mfma_f32_16x16x32_bf16(ap, bv, o[db], 0, 0, 0);
        }
    }
}

// Flash attention, causal, work-balanced: block handles q-tiles (qtl, 31-qtl)
// over one shared kv stream. Output written as bf16 (B,S,D).
__global__ __launch_bounds__(256)
void flash_attn_kernel(const u16* __restrict__ Qh, const u16* __restrict__ Kh,
                       const u16* __restrict__ Vt, u16* __restrict__ attb)
{
    __shared__ __align__(16) u16 Kl[2][64][64];
    __shared__ __align__(16) u16 Vl[2][64][64];
    __shared__ __align__(16) u16 P[4][16][72];

    const int tid  = threadIdx.x;
    const int lane = tid & 63;
    const int wid  = tid >> 6;
    const int lr   = lane & 15, lg = lane >> 4;
    const int qtl  = blockIdx.x;            // 0..15
    const int bh   = blockIdx.y;            // b*H + h
    const int qlo  = qtl, qhi = NT - 1 - qtl;
    const int qbw_lo = qlo*64 + wid*16;
    const int qbw_hi = qhi*64 + wid*16;
    const size_t base = (size_t)bh * SEQ * DKH;

    const int srow = tid >> 3;              // 0..31
    const int se0  = (tid & 7) << 3;        // 0..56
    const int sec  = se0 ^ ((srow & 7) << 3);

    short8 aqlo0 = *(const short8*)&Qh[base + (size_t)(qbw_lo + lr)*DKH +  0 + lg*8];
    short8 aqlo1 = *(const short8*)&Qh[base + (size_t)(qbw_lo + lr)*DKH + 32 + lg*8];
    short8 aqhi0 = *(const short8*)&Qh[base + (size_t)(qbw_hi + lr)*DKH +  0 + lg*8];
    short8 aqhi1 = *(const short8*)&Qh[base + (size_t)(qbw_hi + lr)*DKH + 32 + lg*8];

    f32x4 o_lo[4], o_hi[4];
    float m_lo[4], l_lo[4], m_hi[4], l_hi[4];
    #pragma unroll
    for (int r = 0; r < 4; ++r) { m_lo[r] = -INFINITY; l_lo[r] = 0.f; m_hi[r] = -INFINITY; l_hi[r] = 0.f; }
    #pragma unroll
    for (int db = 0; db < 4; ++db) { f32x4 z = {0.f,0.f,0.f,0.f}; o_lo[db] = z; o_hi[db] = z; }

    const int nc = qhi + 1;

    {
        short8 k0 = *(const short8*)&Kh[base + (size_t)(srow     )*DKH + se0];
        short8 k1 = *(const short8*)&Kh[base + (size_t)(srow + 32)*DKH + se0];
        short8 v0 = *(const short8*)&Vt[base + (size_t)(srow     )*SEQ + se0];
        short8 v1 = *(const short8*)&Vt[base + (size_t)(srow + 32)*SEQ + se0];
        *(short8*)&Kl[0][srow     ][sec] = k0;
        *(short8*)&Kl[0][srow + 32][sec] = k1;
        *(short8*)&Vl[0][srow     ][sec] = v0;
        *(short8*)&Vl[0][srow + 32][sec] = v1;
    }
    __syncthreads();

    int cur = 0;
    for (int c = 0; c < nc; ++c) {
        const int kvb = c * 64;
        short8 nk0, nk1, nv0, nv1;
        const bool pref = (c + 1 < nc);
        if (pref) {
            const int nb_ = kvb + 64;
            nk0 = *(const short8*)&Kh[base + (size_t)(nb_ + srow     )*DKH + se0];
            nk1 = *(const short8*)&Kh[base + (size_t)(nb_ + srow + 32)*DKH + se0];
            nv0 = *(const short8*)&Vt[base + (size_t)(srow     )*SEQ + nb_ + se0];
            nv1 = *(const short8*)&Vt[base + (size_t)(srow + 32)*SEQ + nb_ + se0];
        }

        attn_step(aqhi0, aqhi1, o_hi, m_hi, l_hi, Kl[cur], Vl[cur], P[wid], kvb, qbw_hi, lr, lg);
        if (c <= qlo)
            attn_step(aqlo0, aqlo1, o_lo, m_lo, l_lo, Kl[cur], Vl[cur], P[wid], kvb, qbw_lo, lr, lg);

        __syncthreads();
        if (pref) {
            *(short8*)&Kl[cur^1][srow     ][sec] = nk0;
            *(short8*)&Kl[cur^1][srow + 32][sec] = nk1;
            *(short8*)&Vl[cur^1][srow     ][sec] = nv0;
            *(short8*)&Vl[cur^1][srow + 32][sec] = nv1;
        }
        __syncthreads();
        cur ^= 1;
    }

    const int b = bh >> 4, h = bh & 15;
    #pragma unroll
    for (int db = 0; db < 4; ++db) {
        #pragma unroll
        for (int r = 0; r < 4; ++r) {
            const int slo = qbw_lo + lg*4 + r;
            const int shi = qbw_hi + lg*4 + r;
            attb[((size_t)(b*SEQ + slo))*D_MODEL + h*64 + db*16 + lr] = f2bf(o_lo[db][r] / l_lo[r]);
            attb[((size_t)(b*SEQ + shi))*D_MODEL + h*64 + db*16 + lr] = f2bf(o_hi[db][r] / l_hi[r]);
        }
    }
}

extern "C" void kernel_launch(void* const* d_in, const int* in_sizes, int n_in,
                              void* d_out, int out_size, void* d_ws, size_t ws_size,
                              hipStream_t stream)
{
    const float* q   = (const float*)d_in[0];
    const float* k   = (const float*)d_in[1];
    const float* v   = (const float*)d_in[2];
    // d_in[3] = mask (causal tril) — computed analytically in-kernel
    const float* w_q = (const float*)d_in[4];
    const float* b_q = (const float*)d_in[5];
    const float* w_k = (const float*)d_in[6];
    const float* b_k = (const float*)d_in[7];
    const float* w_v = (const float*)d_in[8];
    const float* b_v = (const float*)d_in[9];
    const float* w_o = (const float*)d_in[10];
    const float* b_o = (const float*)d_in[11];

    char* ws = (char*)d_ws;
    const size_t MB = 1024*1024;
    u16* Qh   = (u16*)(ws +  0*MB);   // bf16 (B,H,S,dk)
    u16* Kh   = (u16*)(ws +  8*MB);   // bf16 (B,H,S,dk)
    u16* Vt   = (u16*)(ws + 16*MB);   // bf16 (B,H,dk,S)
    u16* qb   = (u16*)(ws + 24*MB);   // bf16 (M,K); aliased as attb after Q-proj
    u16* kb   = (u16*)(ws + 32*MB);
    u16* vb   = (u16*)(ws + 40*MB);
    u16* wqb  = (u16*)(ws + 48*MB);
    u16* wkb  = (u16*)(ws + 50*MB);
    u16* wvb  = (u16*)(ws + 52*MB);
    u16* wob  = (u16*)(ws + 54*MB);   // ws usage: 56 MiB
    u16* attb = qb;                   // qb is dead after the Q projection

    const int M = BATCH * SEQ, N = D_MODEL, K = D_MODEL;
    dim3 gg(M/128, N/128);

    convert_kernel<<<2048, 256, 0, stream>>>(q, k, v, w_q, w_k, w_v, w_o,
                                             qb, kb, vb, wqb, wkb, wvb, wob);
    // Q projection carries the 1/sqrt(dk)=0.125 score scale (exact in bf16)
    gemm_bf16_kernel<1><<<gg, 256, 0, stream>>>(qb, wqb, b_q, 0.125f, Qh, M, N, K);
    gemm_bf16_kernel<1><<<gg, 256, 0, stream>>>(kb, wkb, b_k, 1.0f,   Kh, M, N, K);
    gemm_bf16_kernel<2><<<gg, 256, 0, stream>>>(vb, wvb, b_v, 1.0f,   Vt, M, N, K);
    flash_attn_kernel<<<dim3(NT/2, BATCH*N_HEADS), 256, 0, stream>>>(Qh, Kh, Vt, attb);
    gemm_bf16_kernel<0><<<gg, 256, 0, stream>>>(attb, wob, b_o, 1.0f, d_out, M, N, K);
}

// Round 6
// 145.803 us; speedup vs baseline: 2.4655x; 1.2630x over previous
//
#include <hip/hip_runtime.h>
#include <math.h>

#define D_MODEL 1024
#define N_HEADS 16
#define DKH     64
#define BATCH   2
#define SEQ     2048
#define NT      (SEQ/64)          // 32 q-tiles of 64

typedef unsigned short u16;
typedef __attribute__((ext_vector_type(8))) short short8;
typedef __attribute__((ext_vector_type(4))) float f32x4;

__device__ __forceinline__ u16 f2bf(float f) {
    unsigned u = __float_as_uint(f);
    u += 0x7fffu + ((u >> 16) & 1u);
    return (u16)(u >> 16);
}

__device__ __forceinline__ void gll16(const void* g, void* l) {
    __builtin_amdgcn_global_load_lds((const __attribute__((address_space(1))) void*)g,
                                     (__attribute__((address_space(3))) void*)l, 16, 0, 0);
}

// ---------------------------------------------------------------------------
// fp32 -> bf16 convert: q,k,v (4M elems each) + w_q,w_k,w_v,w_o (1M each)
// ---------------------------------------------------------------------------
__global__ __launch_bounds__(256)
void convert_kernel(const float* __restrict__ q, const float* __restrict__ k,
                    const float* __restrict__ v, const float* __restrict__ wq,
                    const float* __restrict__ wk, const float* __restrict__ wv,
                    const float* __restrict__ wo,
                    u16* __restrict__ qb, u16* __restrict__ kb, u16* __restrict__ vb,
                    u16* __restrict__ wqb, u16* __restrict__ wkb,
                    u16* __restrict__ wvb, u16* __restrict__ wob)
{
    const size_t NV = ((size_t)16 << 20) >> 3;   // total 16M elems in vec8 units
    for (size_t i = (size_t)blockIdx.x * blockDim.x + threadIdx.x; i < NV;
         i += (size_t)gridDim.x * blockDim.x) {
        const size_t e = i << 3;
        const float* s; u16* d; size_t off;
        if (e < ((size_t)12 << 20)) {
            const int seg = (int)(e >> 22);
            off = e & (((size_t)1 << 22) - 1);
            s = seg == 0 ? q : seg == 1 ? k : v;
            d = seg == 0 ? qb : seg == 1 ? kb : vb;
        } else {
            const size_t r = e - ((size_t)12 << 20);
            const int seg = (int)(r >> 20);
            off = r & (((size_t)1 << 20) - 1);
            s = seg == 0 ? wq : seg == 1 ? wk : seg == 2 ? wv : wo;
            d = seg == 0 ? wqb : seg == 1 ? wkb : seg == 2 ? wvb : wob;
        }
        const float4 f0 = *(const float4*)(s + off);
        const float4 f1 = *(const float4*)(s + off + 4);
        short8 o;
        o[0]=(short)f2bf(f0.x); o[1]=(short)f2bf(f0.y); o[2]=(short)f2bf(f0.z); o[3]=(short)f2bf(f0.w);
        o[4]=(short)f2bf(f1.x); o[5]=(short)f2bf(f1.y); o[6]=(short)f2bf(f1.z); o[7]=(short)f2bf(f1.w);
        *(short8*)(d + off) = o;
    }
}

// ---------------------------------------------------------------------------
// GEMM core: 128x128 tile, BK=32, 4 waves, global_load_lds staging.
// ---------------------------------------------------------------------------
#define GEMM_PREAMBLE                                                            \
    __shared__ __align__(16) u16 As[2][128][32];                                 \
    __shared__ __align__(16) u16 Bs[2][128][32];                                 \
    const int tid  = threadIdx.x;                                                \
    const int lane = tid & 63;                                                   \
    const int wid  = tid >> 6;                                                   \
    const int wm   = wid >> 1, wn = wid & 1;                                     \
    const int lr   = lane & 15, lg = lane >> 4;                                  \
    const int mb   = blockIdx.x * 128, nb = blockIdx.y * 128;                    \
    const int g_row = lane >> 2;                                                 \
    const int g_col = (lane & 3) << 3;                                           \
    const u16* Ab = A  + (size_t)mb * K;                                         \
    const u16* Bb = Bw + (size_t)nb * K;                                         \
    f32x4 acc[4][4];                                                             \
    _Pragma("unroll")                                                            \
    for (int i = 0; i < 4; ++i)                                                  \
        _Pragma("unroll")                                                        \
        for (int j = 0; j < 4; ++j) { f32x4 z = {0.f,0.f,0.f,0.f}; acc[i][j] = z; }

#define STAGE(buf, kt)                                                           \
    {                                                                            \
        _Pragma("unroll")                                                        \
        for (int t = 0; t < 2; ++t) {                                            \
            const int r0 = t*64 + wid*16;                                        \
            gll16(&Ab[(size_t)(r0 + g_row)*K + (kt) + g_col], &As[buf][r0][0]);  \
            gll16(&Bb[(size_t)(r0 + g_row)*K + (kt) + g_col], &Bs[buf][r0][0]);  \
        }                                                                        \
    }

#define GEMM_MAINLOOP                                                            \
    STAGE(0, 0)                                                                  \
    __syncthreads();                                                             \
    const int NK = K >> 5;                                                       \
    for (int it = 0; it < NK; ++it) {                                            \
        const int c = it & 1;                                                    \
        if (it + 1 < NK) STAGE(c ^ 1, (it + 1) << 5)                             \
        short8 a[4], b[4];                                                       \
        _Pragma("unroll")                                                        \
        for (int i = 0; i < 4; ++i) a[i] = *(const short8*)&As[c][wm*64 + i*16 + lr][lg*8]; \
        _Pragma("unroll")                                                        \
        for (int j = 0; j < 4; ++j) b[j] = *(const short8*)&Bs[c][wn*64 + j*16 + lr][lg*8]; \
        _Pragma("unroll")                                                        \
        for (int i = 0; i < 4; ++i)                                              \
            _Pragma("unroll")                                                    \
            for (int j = 0; j < 4; ++j)                                          \
                acc[i][j] = __builtin_amdgcn_mfma_f32_16x16x32_bf16(a[i], b[j], acc[i][j], 0, 0, 0); \
        __syncthreads();                                                         \
    }

// Batched Q/K/V projection: blockIdx.z selects {q,k,v}.  3 blocks/CU.
__global__ __launch_bounds__(256, 3)
void gemm_qkv_kernel(const u16* __restrict__ qb, const u16* __restrict__ kb,
                     const u16* __restrict__ vb, const u16* __restrict__ wqb,
                     const u16* __restrict__ wkb, const u16* __restrict__ wvb,
                     const float* __restrict__ b_q, const float* __restrict__ b_k,
                     const float* __restrict__ b_v,
                     u16* __restrict__ Qh, u16* __restrict__ Kh, u16* __restrict__ Vt,
                     int M, int N, int K)
{
    const int z = blockIdx.z;
    const u16* A    = z == 0 ? qb  : z == 1 ? kb  : vb;
    const u16* Bw   = z == 0 ? wqb : z == 1 ? wkb : wvb;
    const float* bias = z == 0 ? b_q : z == 1 ? b_k : b_v;
    u16* dst        = z == 0 ? Qh  : z == 1 ? Kh  : Vt;
    const float scale = z == 0 ? 0.125f : 1.0f;   // fold 1/sqrt(dk) into Q

    GEMM_PREAMBLE
    GEMM_MAINLOOP

    #pragma unroll
    for (int i = 0; i < 4; ++i) {
        #pragma unroll
        for (int j = 0; j < 4; ++j) {
            const int mbase = mb + wm*64 + i*16 + lg*4;
            const int n     = nb + wn*64 + j*16 + lr;
            const float bn  = bias[n];
            const int h = n >> 6, d = n & 63;
            #pragma unroll
            for (int r = 0; r < 4; ++r) {
                const int m = mbase + r;
                const int b = m >> 11, s = m & (SEQ - 1);
                const float val = (acc[i][j][r] + bn) * scale;
                if (z == 2)   // V transposed (B,H,dk,S)
                    dst[(((size_t)(b*N_HEADS + h))*DKH + d)*SEQ + s] = f2bf(val);
                else          // Q,K (B,H,S,dk)
                    dst[(((size_t)(b*N_HEADS + h))*SEQ + s)*DKH + d] = f2bf(val);
            }
        }
    }
}

// Output projection: dst fp32 (M,N) = acc + bias
__global__ __launch_bounds__(256)
void gemm_out_kernel(const u16* __restrict__ A, const u16* __restrict__ Bw,
                     const float* __restrict__ bias, float* __restrict__ dst,
                     int M, int N, int K)
{
    GEMM_PREAMBLE
    GEMM_MAINLOOP

    #pragma unroll
    for (int i = 0; i < 4; ++i) {
        #pragma unroll
        for (int j = 0; j < 4; ++j) {
            const int mbase = mb + wm*64 + i*16 + lg*4;
            const int n     = nb + wn*64 + j*16 + lr;
            const float bn  = bias[n];
            #pragma unroll
            for (int r = 0; r < 4; ++r)
                dst[(size_t)(mbase + r) * N + n] = acc[i][j][r] + bn;
        }
    }
}

// ---------------------------------------------------------------------------
// one attention step: 16 q rows x 64 kv, online softmax (defer-max THR=8),
// row-sum via MFMA ones-column, O += P V
// ---------------------------------------------------------------------------
__device__ __forceinline__ void attn_step(
    const short8& aq0, const short8& aq1,
    f32x4 (&o)[4], f32x4& osum, float (&m_run)[4],
    const u16 (*__restrict__ Kl)[64], const u16 (*__restrict__ Vl)[64],
    u16 (*__restrict__ Pw)[72],
    int kvb, int qbw, int lr, int lg)
{
    const int ksw = (lr & 7) << 3;
    f32x4 s[4];
    #pragma unroll
    for (int cb = 0; cb < 4; ++cb) {
        const int kr = cb*16 + lr;
        f32x4 z = {0.f,0.f,0.f,0.f};
        short8 k0 = *(const short8*)&Kl[kr][( 0 + lg*8) ^ ksw];
        short8 k1 = *(const short8*)&Kl[kr][(32 + lg*8) ^ ksw];
        z = __builtin_amdgcn_mfma_f32_16x16x32_bf16(aq0, k0, z, 0, 0, 0);
        z = __builtin_amdgcn_mfma_f32_16x16x32_bf16(aq1, k1, z, 0, 0, 0);
        s[cb] = z;
    }

    if (kvb + 63 > qbw) {
        #pragma unroll
        for (int cb = 0; cb < 4; ++cb)
            #pragma unroll
            for (int r = 0; r < 4; ++r)
                if (kvb + cb*16 + lr > qbw + lg*4 + r) s[cb][r] = -INFINITY;
    }

    // tile row-max (16-lane-group shuffle reduce)
    float tm[4];
    #pragma unroll
    for (int r = 0; r < 4; ++r) {
        float t = fmaxf(fmaxf(s[0][r], s[1][r]), fmaxf(s[2][r], s[3][r]));
        #pragma unroll
        for (int off = 1; off < 16; off <<= 1) t = fmaxf(t, __shfl_xor(t, off));
        tm[r] = t;
    }
    // defer-max: rescale only when some row's max grew past m+8
    int need = 0;
    #pragma unroll
    for (int r = 0; r < 4; ++r) need |= (tm[r] > m_run[r] + 8.f) ? 1 : 0;
    if (__any(need)) {
        #pragma unroll
        for (int r = 0; r < 4; ++r) {
            const float mnew  = fmaxf(m_run[r], tm[r]);
            const float alpha = __expf(m_run[r] - mnew);   // -inf -> 0
            m_run[r] = mnew;
            osum[r] *= alpha;
            #pragma unroll
            for (int db = 0; db < 4; ++db) o[db][r] *= alpha;
        }
    }
    // P = exp(s - m), bf16, to per-wave LDS
    #pragma unroll
    for (int r = 0; r < 4; ++r)
        #pragma unroll
        for (int cb = 0; cb < 4; ++cb)
            Pw[lg*4 + r][cb*16 + lr] = f2bf(__expf(s[cb][r] - m_run[r]));

    // O += P @ V ; osum += P @ ones  (row sum by matrix pipe)
    short8 vone;
    #pragma unroll
    for (int j = 0; j < 8; ++j) vone[j] = (short)0x3F80;   // bf16 1.0
    #pragma unroll
    for (int ks = 0; ks < 2; ++ks) {
        short8 ap = *(short8*)&Pw[lr][ks*32 + lg*8];
        #pragma unroll
        for (int db = 0; db < 4; ++db) {
            const int vr = db*16 + lr;
            short8 bv = *(const short8*)&Vl[vr][(ks*32 + lg*8) ^ ksw];
            o[db] = __builtin_amdgcn_mfma_f32_16x16x32_bf16(ap, bv, o[db], 0, 0, 0);
        }
        osum = __builtin_amdgcn_mfma_f32_16x16x32_bf16(ap, vone, osum, 0, 0, 0);
    }
}

// Flash attention, causal, work-balanced: block handles q-tiles (qtl, 31-qtl)
// over one shared kv stream. Output written as bf16 (B,S,D).
__global__ __launch_bounds__(256)
void flash_attn_kernel(const u16* __restrict__ Qh, const u16* __restrict__ Kh,
                       const u16* __restrict__ Vt, u16* __restrict__ attb)
{
    __shared__ __align__(16) u16 Kl[2][64][64];
    __shared__ __align__(16) u16 Vl[2][64][64];
    __shared__ __align__(16) u16 P[4][16][72];

    const int tid  = threadIdx.x;
    const int lane = tid & 63;
    const int wid  = tid >> 6;
    const int lr   = lane & 15, lg = lane >> 4;
    const int qtl  = blockIdx.x;            // 0..15
    const int bh   = blockIdx.y;            // b*H + h
    const int qlo  = qtl, qhi = NT - 1 - qtl;
    const int qbw_lo = qlo*64 + wid*16;
    const int qbw_hi = qhi*64 + wid*16;
    const size_t base = (size_t)bh * SEQ * DKH;

    const int srow = tid >> 3;              // 0..31
    const int se0  = (tid & 7) << 3;        // 0..56
    const int sec  = se0 ^ ((srow & 7) << 3);

    short8 aqlo0 = *(const short8*)&Qh[base + (size_t)(qbw_lo + lr)*DKH +  0 + lg*8];
    short8 aqlo1 = *(const short8*)&Qh[base + (size_t)(qbw_lo + lr)*DKH + 32 + lg*8];
    short8 aqhi0 = *(const short8*)&Qh[base + (size_t)(qbw_hi + lr)*DKH +  0 + lg*8];
    short8 aqhi1 = *(const short8*)&Qh[base + (size_t)(qbw_hi + lr)*DKH + 32 + lg*8];

    f32x4 o_lo[4], o_hi[4], osum_lo, osum_hi;
    float m_lo[4], m_hi[4];
    #pragma unroll
    for (int r = 0; r < 4; ++r) { m_lo[r] = -INFINITY; m_hi[r] = -INFINITY; }
    {
        f32x4 z = {0.f,0.f,0.f,0.f};
        osum_lo = z; osum_hi = z;
        #pragma unroll
        for (int db = 0; db < 4; ++db) { o_lo[db] = z; o_hi[db] = z; }
    }

    const int nc = qhi + 1;

    {
        short8 k0 = *(const short8*)&Kh[base + (size_t)(srow     )*DKH + se0];
        short8 k1 = *(const short8*)&Kh[base + (size_t)(srow + 32)*DKH + se0];
        short8 v0 = *(const short8*)&Vt[base + (size_t)(srow     )*SEQ + se0];
        short8 v1 = *(const short8*)&Vt[base + (size_t)(srow + 32)*SEQ + se0];
        *(short8*)&Kl[0][srow     ][sec] = k0;
        *(short8*)&Kl[0][srow + 32][sec] = k1;
        *(short8*)&Vl[0][srow     ][sec] = v0;
        *(short8*)&Vl[0][srow + 32][sec] = v1;
    }
    __syncthreads();

    int cur = 0;
    for (int c = 0; c < nc; ++c) {
        const int kvb = c * 64;
        short8 nk0, nk1, nv0, nv1;
        const bool pref = (c + 1 < nc);
        if (pref) {
            const int nb_ = kvb + 64;
            nk0 = *(const short8*)&Kh[base + (size_t)(nb_ + srow     )*DKH + se0];
            nk1 = *(const short8*)&Kh[base + (size_t)(nb_ + srow + 32)*DKH + se0];
            nv0 = *(const short8*)&Vt[base + (size_t)(srow     )*SEQ + nb_ + se0];
            nv1 = *(const short8*)&Vt[base + (size_t)(srow + 32)*SEQ + nb_ + se0];
        }

        attn_step(aqhi0, aqhi1, o_hi, osum_hi, m_hi, Kl[cur], Vl[cur], P[wid], kvb, qbw_hi, lr, lg);
        if (c <= qlo)
            attn_step(aqlo0, aqlo1, o_lo, osum_lo, m_lo, Kl[cur], Vl[cur], P[wid], kvb, qbw_lo, lr, lg);

        __syncthreads();
        if (pref) {
            *(short8*)&Kl[cur^1][srow     ][sec] = nk0;
            *(short8*)&Kl[cur^1][srow + 32][sec] = nk1;
            *(short8*)&Vl[cur^1][srow     ][sec] = nv0;
            *(short8*)&Vl[cur^1][srow + 32][sec] = nv1;
        }
        __syncthreads();
        cur ^= 1;
    }

    const int b = bh >> 4, h = bh & 15;
    float inv_lo[4], inv_hi[4];
    #pragma unroll
    for (int r = 0; r < 4; ++r) { inv_lo[r] = 1.f / osum_lo[r]; inv_hi[r] = 1.f / osum_hi[r]; }
    #pragma unroll
    for (int db = 0; db < 4; ++db) {
        #pragma unroll
        for (int r = 0; r < 4; ++r) {
            const int slo = qbw_lo + lg*4 + r;
            const int shi = qbw_hi + lg*4 + r;
            attb[((size_t)(b*SEQ + slo))*D_MODEL + h*64 + db*16 + lr] = f2bf(o_lo[db][r] * inv_lo[r]);
            attb[((size_t)(b*SEQ + shi))*D_MODEL + h*64 + db*16 + lr] = f2bf(o_hi[db][r] * inv_hi[r]);
        }
    }
}

extern "C" void kernel_launch(void* const* d_in, const int* in_sizes, int n_in,
                              void* d_out, int out_size, void* d_ws, size_t ws_size,
                              hipStream_t stream)
{
    const float* q   = (const float*)d_in[0];
    const float* k   = (const float*)d_in[1];
    const float* v   = (const float*)d_in[2];
    // d_in[3] = mask (causal tril) — computed analytically in-kernel
    const float* w_q = (const float*)d_in[4];
    const float* b_q = (const float*)d_in[5];
    const float* w_k = (const float*)d_in[6];
    const float* b_k = (const float*)d_in[7];
    const float* w_v = (const float*)d_in[8];
    const float* b_v = (const float*)d_in[9];
    const float* w_o = (const float*)d_in[10];
    const float* b_o = (const float*)d_in[11];

    char* ws = (char*)d_ws;
    const size_t MB = 1024*1024;
    u16* Qh   = (u16*)(ws +  0*MB);   // bf16 (B,H,S,dk)
    u16* Kh   = (u16*)(ws +  8*MB);   // bf16 (B,H,S,dk)
    u16* Vt   = (u16*)(ws + 16*MB);   // bf16 (B,H,dk,S)
    u16* qb   = (u16*)(ws + 24*MB);   // bf16 (M,K); aliased as attb after Q-proj
    u16* kb   = (u16*)(ws + 32*MB);
    u16* vb   = (u16*)(ws + 40*MB);
    u16* wqb  = (u16*)(ws + 48*MB);
    u16* wkb  = (u16*)(ws + 50*MB);
    u16* wvb  = (u16*)(ws + 52*MB);
    u16* wob  = (u16*)(ws + 54*MB);   // ws usage: 56 MiB
    u16* attb = qb;                   // qb is dead after the Q projection

    const int M = BATCH * SEQ, N = D_MODEL, K = D_MODEL;

    convert_kernel<<<2048, 256, 0, stream>>>(q, k, v, w_q, w_k, w_v, w_o,
                                             qb, kb, vb, wqb, wkb, wvb, wob);
    gemm_qkv_kernel<<<dim3(M/128, N/128, 3), 256, 0, stream>>>(
        qb, kb, vb, wqb, wkb, wvb, b_q, b_k, b_v, Qh, Kh, Vt, M, N, K);
    flash_attn_kernel<<<dim3(NT/2, BATCH*N_HEADS), 256, 0, stream>>>(Qh, Kh, Vt, attb);
    gemm_out_kernel<<<dim3(M/128, N/128), 256, 0, stream>>>(attb, wob, b_o, (float*)d_out, M, N, K);
}

// Round 7
// 141.160 us; speedup vs baseline: 2.5466x; 1.0329x over previous
//
#include <hip/hip_runtime.h>
#include <math.h>

#define D_MODEL 1024
#define N_HEADS 16
#define DKH     64
#define BATCH   2
#define SEQ     2048
#define NT      (SEQ/64)          // 32 q-tiles of 64

typedef unsigned short u16;
typedef __attribute__((ext_vector_type(8))) short short8;
typedef __attribute__((ext_vector_type(4))) float f32x4;

__device__ __forceinline__ u16 f2bf(float f) {
    unsigned u = __float_as_uint(f);
    u += 0x7fffu + ((u >> 16) & 1u);
    return (u16)(u >> 16);
}

__device__ __forceinline__ void gll16(const void* g, void* l) {
    __builtin_amdgcn_global_load_lds((const __attribute__((address_space(1))) void*)g,
                                     (__attribute__((address_space(3))) void*)l, 16, 0, 0);
}

// ---------------------------------------------------------------------------
// fp32 -> bf16 convert: q,k,v (4M elems each) + w_q,w_k,w_v,w_o (1M each)
// ---------------------------------------------------------------------------
__global__ __launch_bounds__(256)
void convert_kernel(const float* __restrict__ q, const float* __restrict__ k,
                    const float* __restrict__ v, const float* __restrict__ wq,
                    const float* __restrict__ wk, const float* __restrict__ wv,
                    const float* __restrict__ wo,
                    u16* __restrict__ qb, u16* __restrict__ kb, u16* __restrict__ vb,
                    u16* __restrict__ wqb, u16* __restrict__ wkb,
                    u16* __restrict__ wvb, u16* __restrict__ wob)
{
    const size_t NV = ((size_t)16 << 20) >> 3;   // total 16M elems in vec8 units
    for (size_t i = (size_t)blockIdx.x * blockDim.x + threadIdx.x; i < NV;
         i += (size_t)gridDim.x * blockDim.x) {
        const size_t e = i << 3;
        const float* s; u16* d; size_t off;
        if (e < ((size_t)12 << 20)) {
            const int seg = (int)(e >> 22);
            off = e & (((size_t)1 << 22) - 1);
            s = seg == 0 ? q : seg == 1 ? k : v;
            d = seg == 0 ? qb : seg == 1 ? kb : vb;
        } else {
            const size_t r = e - ((size_t)12 << 20);
            const int seg = (int)(r >> 20);
            off = r & (((size_t)1 << 20) - 1);
            s = seg == 0 ? wq : seg == 1 ? wk : seg == 2 ? wv : wo;
            d = seg == 0 ? wqb : seg == 1 ? wkb : seg == 2 ? wvb : wob;
        }
        const float4 f0 = *(const float4*)(s + off);
        const float4 f1 = *(const float4*)(s + off + 4);
        short8 o;
        o[0]=(short)f2bf(f0.x); o[1]=(short)f2bf(f0.y); o[2]=(short)f2bf(f0.z); o[3]=(short)f2bf(f0.w);
        o[4]=(short)f2bf(f1.x); o[5]=(short)f2bf(f1.y); o[6]=(short)f2bf(f1.z); o[7]=(short)f2bf(f1.w);
        *(short8*)(d + off) = o;
    }
}

// ---------------------------------------------------------------------------
// GEMM core: 128x128 tile, BK=32, 4 waves, global_load_lds staging.
// ---------------------------------------------------------------------------
#define GEMM_PREAMBLE                                                            \
    __shared__ __align__(16) u16 As[2][128][32];                                 \
    __shared__ __align__(16) u16 Bs[2][128][32];                                 \
    const int tid  = threadIdx.x;                                                \
    const int lane = tid & 63;                                                   \
    const int wid  = tid >> 6;                                                   \
    const int wm   = wid >> 1, wn = wid & 1;                                     \
    const int lr   = lane & 15, lg = lane >> 4;                                  \
    const int mb   = blockIdx.x * 128, nb = blockIdx.y * 128;                    \
    const int g_row = lane >> 2;                                                 \
    const int g_col = (lane & 3) << 3;                                           \
    const u16* Ab = A  + (size_t)mb * K;                                         \
    const u16* Bb = Bw + (size_t)nb * K;                                         \
    f32x4 acc[4][4];                                                             \
    _Pragma("unroll")                                                            \
    for (int i = 0; i < 4; ++i)                                                  \
        _Pragma("unroll")                                                        \
        for (int j = 0; j < 4; ++j) { f32x4 z = {0.f,0.f,0.f,0.f}; acc[i][j] = z; }

#define STAGE(buf, kt)                                                           \
    {                                                                            \
        _Pragma("unroll")                                                        \
        for (int t = 0; t < 2; ++t) {                                            \
            const int r0 = t*64 + wid*16;                                        \
            gll16(&Ab[(size_t)(r0 + g_row)*K + (kt) + g_col], &As[buf][r0][0]);  \
            gll16(&Bb[(size_t)(r0 + g_row)*K + (kt) + g_col], &Bs[buf][r0][0]);  \
        }                                                                        \
    }

#define GEMM_MAINLOOP                                                            \
    STAGE(0, 0)                                                                  \
    __syncthreads();                                                             \
    const int NK = K >> 5;                                                       \
    for (int it = 0; it < NK; ++it) {                                            \
        const int c = it & 1;                                                    \
        if (it + 1 < NK) STAGE(c ^ 1, (it + 1) << 5)                             \
        short8 a[4], b[4];                                                       \
        _Pragma("unroll")                                                        \
        for (int i = 0; i < 4; ++i) a[i] = *(const short8*)&As[c][wm*64 + i*16 + lr][lg*8]; \
        _Pragma("unroll")                                                        \
        for (int j = 0; j < 4; ++j) b[j] = *(const short8*)&Bs[c][wn*64 + j*16 + lr][lg*8]; \
        _Pragma("unroll")                                                        \
        for (int i = 0; i < 4; ++i)                                              \
            _Pragma("unroll")                                                    \
            for (int j = 0; j < 4; ++j)                                          \
                acc[i][j] = __builtin_amdgcn_mfma_f32_16x16x32_bf16(a[i], b[j], acc[i][j], 0, 0, 0); \
        __syncthreads();                                                         \
    }

// Batched Q/K/V projection: blockIdx.z selects {q,k,v}.  3 blocks/CU.
__global__ __launch_bounds__(256, 3)
void gemm_qkv_kernel(const u16* __restrict__ qb, const u16* __restrict__ kb,
                     const u16* __restrict__ vb, const u16* __restrict__ wqb,
                     const u16* __restrict__ wkb, const u16* __restrict__ wvb,
                     const float* __restrict__ b_q, const float* __restrict__ b_k,
                     const float* __restrict__ b_v,
                     u16* __restrict__ Qh, u16* __restrict__ Kh, u16* __restrict__ Vt,
                     int M, int N, int K)
{
    const int z = blockIdx.z;
    const u16* A    = z == 0 ? qb  : z == 1 ? kb  : vb;
    const u16* Bw   = z == 0 ? wqb : z == 1 ? wkb : wvb;
    const float* bias = z == 0 ? b_q : z == 1 ? b_k : b_v;
    u16* dst        = z == 0 ? Qh  : z == 1 ? Kh  : Vt;
    const float scale = z == 0 ? 0.125f : 1.0f;   // fold 1/sqrt(dk) into Q

    GEMM_PREAMBLE
    GEMM_MAINLOOP

    #pragma unroll
    for (int i = 0; i < 4; ++i) {
        #pragma unroll
        for (int j = 0; j < 4; ++j) {
            const int mbase = mb + wm*64 + i*16 + lg*4;
            const int n     = nb + wn*64 + j*16 + lr;
            const float bn  = bias[n];
            const int h = n >> 6, d = n & 63;
            #pragma unroll
            for (int r = 0; r < 4; ++r) {
                const int m = mbase + r;
                const int b = m >> 11, s = m & (SEQ - 1);
                const float val = (acc[i][j][r] + bn) * scale;
                if (z == 2)   // V transposed (B,H,dk,S)
                    dst[(((size_t)(b*N_HEADS + h))*DKH + d)*SEQ + s] = f2bf(val);
                else          // Q,K (B,H,S,dk)
                    dst[(((size_t)(b*N_HEADS + h))*SEQ + s)*DKH + d] = f2bf(val);
            }
        }
    }
}

// Output projection: dst fp32 (M,N) = acc + bias
__global__ __launch_bounds__(256)
void gemm_out_kernel(const u16* __restrict__ A, const u16* __restrict__ Bw,
                     const float* __restrict__ bias, float* __restrict__ dst,
                     int M, int N, int K)
{
    GEMM_PREAMBLE
    GEMM_MAINLOOP

    #pragma unroll
    for (int i = 0; i < 4; ++i) {
        #pragma unroll
        for (int j = 0; j < 4; ++j) {
            const int mbase = mb + wm*64 + i*16 + lg*4;
            const int n     = nb + wn*64 + j*16 + lr;
            const float bn  = bias[n];
            #pragma unroll
            for (int r = 0; r < 4; ++r)
                dst[(size_t)(mbase + r) * N + n] = acc[i][j][r] + bn;
        }
    }
}

// ---------------------------------------------------------------------------
// one attention step: 16 q rows x 64 kv, online softmax (defer-max THR=8),
// row-sum via MFMA ones-column, O += P V
// ---------------------------------------------------------------------------
__device__ __forceinline__ void attn_step(
    const short8& aq0, const short8& aq1,
    f32x4 (&o)[4], f32x4& osum, float (&m_run)[4],
    const u16 (*__restrict__ Kl)[64], const u16 (*__restrict__ Vl)[64],
    u16 (*__restrict__ Pw)[72],
    int kvb, int qbw, int lr, int lg)
{
    const int ksw = (lr & 7) << 3;
    f32x4 s[4];
    #pragma unroll
    for (int cb = 0; cb < 4; ++cb) {
        const int kr = cb*16 + lr;
        f32x4 z = {0.f,0.f,0.f,0.f};
        short8 k0 = *(const short8*)&Kl[kr][( 0 + lg*8) ^ ksw];
        short8 k1 = *(const short8*)&Kl[kr][(32 + lg*8) ^ ksw];
        z = __builtin_amdgcn_mfma_f32_16x16x32_bf16(aq0, k0, z, 0, 0, 0);
        z = __builtin_amdgcn_mfma_f32_16x16x32_bf16(aq1, k1, z, 0, 0, 0);
        s[cb] = z;
    }

    if (kvb + 63 > qbw) {
        #pragma unroll
        for (int cb = 0; cb < 4; ++cb)
            #pragma unroll
            for (int r = 0; r < 4; ++r)
                if (kvb + cb*16 + lr > qbw + lg*4 + r) s[cb][r] = -INFINITY;
    }

    // tile row-max (16-lane-group shuffle reduce)
    float tm[4];
    #pragma unroll
    for (int r = 0; r < 4; ++r) {
        float t = fmaxf(fmaxf(s[0][r], s[1][r]), fmaxf(s[2][r], s[3][r]));
        #pragma unroll
        for (int off = 1; off < 16; off <<= 1) t = fmaxf(t, __shfl_xor(t, off));
        tm[r] = t;
    }
    // defer-max: rescale only when some row's max grew past m+8
    int need = 0;
    #pragma unroll
    for (int r = 0; r < 4; ++r) need |= (tm[r] > m_run[r] + 8.f) ? 1 : 0;
    if (__any(need)) {
        #pragma unroll
        for (int r = 0; r < 4; ++r) {
            const float mnew  = fmaxf(m_run[r], tm[r]);
            const float alpha = __expf(m_run[r] - mnew);   // -inf -> 0
            m_run[r] = mnew;
            osum[r] *= alpha;
            #pragma unroll
            for (int db = 0; db < 4; ++db) o[db][r] *= alpha;
        }
    }
    // P = exp(s - m), bf16, to per-wave LDS
    #pragma unroll
    for (int r = 0; r < 4; ++r)
        #pragma unroll
        for (int cb = 0; cb < 4; ++cb)
            Pw[lg*4 + r][cb*16 + lr] = f2bf(__expf(s[cb][r] - m_run[r]));

    // O += P @ V ; osum += P @ ones  (row sum by matrix pipe)
    short8 vone;
    #pragma unroll
    for (int j = 0; j < 8; ++j) vone[j] = (short)0x3F80;   // bf16 1.0
    #pragma unroll
    for (int ks = 0; ks < 2; ++ks) {
        short8 ap = *(short8*)&Pw[lr][ks*32 + lg*8];
        #pragma unroll
        for (int db = 0; db < 4; ++db) {
            const int vr = db*16 + lr;
            short8 bv = *(const short8*)&Vl[vr][(ks*32 + lg*8) ^ ksw];
            o[db] = __builtin_amdgcn_mfma_f32_16x16x32_bf16(ap, bv, o[db], 0, 0, 0);
        }
        osum = __builtin_amdgcn_mfma_f32_16x16x32_bf16(ap, vone, osum, 0, 0, 0);
    }
}

// Flash attention, causal. 512 threads = 8 waves; block owns a 128-row q-tile
// (wave w: rows qt*128 + w*16 ..+15) sharing one kv stream staged in LDS.
// Each wave does ONE attn_step per staged tile -> short critical path, high
// wave-level overlap. LPT dispatch: big tiles (high t) launch first.
__global__ __launch_bounds__(512, 4)
void flash_attn_kernel(const u16* __restrict__ Qh, const u16* __restrict__ Kh,
                       const u16* __restrict__ Vt, u16* __restrict__ attb)
{
    __shared__ __align__(16) u16 Kl[2][64][64];
    __shared__ __align__(16) u16 Vl[2][64][64];
    __shared__ __align__(16) u16 P[8][16][72];

    const int tid  = threadIdx.x;
    const int lane = tid & 63;
    const int wid  = tid >> 6;              // 0..7
    const int lr   = lane & 15, lg = lane >> 4;
    const int bh   = blockIdx.x;            // b*H + h
    const int t    = 15 - blockIdx.y;       // q-tile of 128, LPT order
    const int qbw  = t*128 + wid*16;        // wave's first q row
    const size_t base = (size_t)bh * SEQ * DKH;

    const int srow = tid >> 3;              // 0..63 (512 threads)
    const int se0  = (tid & 7) << 3;        // 0..56
    const int sec  = se0 ^ ((srow & 7) << 3);

    short8 aq0 = *(const short8*)&Qh[base + (size_t)(qbw + lr)*DKH +  0 + lg*8];
    short8 aq1 = *(const short8*)&Qh[base + (size_t)(qbw + lr)*DKH + 32 + lg*8];

    f32x4 o[4], osum;
    float m_run[4];
    #pragma unroll
    for (int r = 0; r < 4; ++r) m_run[r] = -INFINITY;
    {
        f32x4 z = {0.f,0.f,0.f,0.f};
        osum = z;
        #pragma unroll
        for (int db = 0; db < 4; ++db) o[db] = z;
    }

    const int nc = 2 * (t + 1);             // kv tiles of 64 (causal, 128 rows)

    {
        short8 k0 = *(const short8*)&Kh[base + (size_t)srow*DKH + se0];
        short8 v0 = *(const short8*)&Vt[base + (size_t)srow*SEQ + se0];
        *(short8*)&Kl[0][srow][sec] = k0;
        *(short8*)&Vl[0][srow][sec] = v0;
    }
    __syncthreads();

    int cur = 0;
    for (int c = 0; c < nc; ++c) {
        const int kvb = c * 64;
        short8 nk0, nv0;
        const bool pref = (c + 1 < nc);
        if (pref) {
            const int nb_ = kvb + 64;
            nk0 = *(const short8*)&Kh[base + (size_t)(nb_ + srow)*DKH + se0];
            nv0 = *(const short8*)&Vt[base + (size_t)srow*SEQ + nb_ + se0];
        }

        if (kvb <= qbw + 15)    // wave active while kv range intersects causal
            attn_step(aq0, aq1, o, osum, m_run, Kl[cur], Vl[cur], P[wid], kvb, qbw, lr, lg);

        __syncthreads();
        if (pref) {
            *(short8*)&Kl[cur^1][srow][sec] = nk0;
            *(short8*)&Vl[cur^1][srow][sec] = nv0;
        }
        __syncthreads();
        cur ^= 1;
    }

    const int b = bh >> 4, h = bh & 15;
    float inv[4];
    #pragma unroll
    for (int r = 0; r < 4; ++r) inv[r] = 1.f / osum[r];
    #pragma unroll
    for (int db = 0; db < 4; ++db) {
        #pragma unroll
        for (int r = 0; r < 4; ++r) {
            const int s_ = qbw + lg*4 + r;
            attb[((size_t)(b*SEQ + s_))*D_MODEL + h*64 + db*16 + lr] = f2bf(o[db][r] * inv[r]);
        }
    }
}

extern "C" void kernel_launch(void* const* d_in, const int* in_sizes, int n_in,
                              void* d_out, int out_size, void* d_ws, size_t ws_size,
                              hipStream_t stream)
{
    const float* q   = (const float*)d_in[0];
    const float* k   = (const float*)d_in[1];
    const float* v   = (const float*)d_in[2];
    // d_in[3] = mask (causal tril) — computed analytically in-kernel
    const float* w_q = (const float*)d_in[4];
    const float* b_q = (const float*)d_in[5];
    const float* w_k = (const float*)d_in[6];
    const float* b_k = (const float*)d_in[7];
    const float* w_v = (const float*)d_in[8];
    const float* b_v = (const float*)d_in[9];
    const float* w_o = (const float*)d_in[10];
    const float* b_o = (const float*)d_in[11];

    char* ws = (char*)d_ws;
    const size_t MB = 1024*1024;
    u16* Qh   = (u16*)(ws +  0*MB);   // bf16 (B,H,S,dk)
    u16* Kh   = (u16*)(ws +  8*MB);   // bf16 (B,H,S,dk)
    u16* Vt   = (u16*)(ws + 16*MB);   // bf16 (B,H,dk,S)
    u16* qb   = (u16*)(ws + 24*MB);   // bf16 (M,K); aliased as attb after Q-proj
    u16* kb   = (u16*)(ws + 32*MB);
    u16* vb   = (u16*)(ws + 40*MB);
    u16* wqb  = (u16*)(ws + 48*MB);
    u16* wkb  = (u16*)(ws + 50*MB);
    u16* wvb  = (u16*)(ws + 52*MB);
    u16* wob  = (u16*)(ws + 54*MB);   // ws usage: 56 MiB
    u16* attb = qb;                   // qb is dead after the Q projection

    const int M = BATCH * SEQ, N = D_MODEL, K = D_MODEL;

    convert_kernel<<<2048, 256, 0, stream>>>(q, k, v, w_q, w_k, w_v, w_o,
                                             qb, kb, vb, wqb, wkb, wvb, wob);
    gemm_qkv_kernel<<<dim3(M/128, N/128, 3), 256, 0, stream>>>(
        qb, kb, vb, wqb, wkb, wvb, b_q, b_k, b_v, Qh, Kh, Vt, M, N, K);
    flash_attn_kernel<<<dim3(BATCH*N_HEADS, 16), 512, 0, stream>>>(Qh, Kh, Vt, attb);
    gemm_out_kernel<<<dim3(M/128, N/128), 256, 0, stream>>>(attb, wob, b_o, (float*)d_out, M, N, K);
}